// Round 6
// baseline (2124.852 us; speedup 1.0000x reference)
//
#include <hip/hip_runtime.h>
#include <cstdint>
#include <cstddef>

// Decoder_55654186222328 — MI355X, R14: 4 barriers/step + P4 2-stage pipeline +
// merged prologue.
// R13 post-mortem: PASS 1007us decoder (trans-op hazard fixed via builtins).
// Latency-bound now: ~5-9K cycles/wave-step of issue work vs ~25-30K observed;
// gap = 5 barrier drains/step + serial S->exp->pack->PV chain in P4 + LDS
// latency at P6 head + ~286us of serialized independent prologue launches.
// R14 (all pure reorderings, zero numeric diff):
//  * s_h(t) reads (HH A-frags + old-h) hoisted to P1 phase; P1-end barrier
//    drain makes them block-wide complete -> P6 mid-barrier REMOVED (5->4).
//  * P4: explicit 2-stage pipeline — S-MFMAs for chunk c+1 (kB prefetched
//    2 ahead) issue before exp/pack/PV of chunk c.
//  * One prep_kernel (block-role switch: kv | fold_wiho | convert | fold_wq3b)
//    replaces 4 serialized launches -> concurrent, 2 launches total.
//  * P6 batches its 8 o-fragment LDS reads before the MFMA burst.
// 256 blocks (128 b x 2 agent halves of 32) x 512 threads, 1 block/CU,
// LDS 162560 B. VGPR budget: LDS-limited occupancy (8 waves/CU) allows 256.

typedef short short8 __attribute__((ext_vector_type(8)));
typedef float f32x4 __attribute__((ext_vector_type(4)));

#define LOG2E 1.4426950408889634f
#define QSCALE 0.36067376022224085f /* log2(e)/4 */

__device__ __forceinline__ unsigned short f2bf(float f) {
  union { float f; unsigned int u; } v; v.f = f;
  unsigned int u = v.u;
  return (unsigned short)((u + 0x7fffu + ((u >> 16) & 1u)) >> 16);  // RNE
}
__device__ __forceinline__ float fexp2(float x) {
  return __builtin_amdgcn_exp2f(x);   // v_exp_f32, compiler-managed hazards
}
__device__ __forceinline__ float frcp(float x) {
  return __builtin_amdgcn_rcpf(x);    // v_rcp_f32, compiler-managed hazards
}
__device__ __forceinline__ float sigm(float x) {
  return frcp(1.f + fexp2(-LOG2E * x));
}
__device__ __forceinline__ float tanh_f(float x) {
  return 1.f - 2.f * frcp(1.f + fexp2(2.f * LOG2E * x));
}
__device__ __forceinline__ f32x4 splat4(float v) { f32x4 r = {v, v, v, v}; return r; }
__device__ __forceinline__ unsigned char f2fp8(float x) {
  return (unsigned char)__builtin_amdgcn_cvt_pk_fp8_f32(x, x, 0, false);
}
__device__ __forceinline__ f32x4 mfma_fp8(long a, long b, f32x4 c) {
  return __builtin_amdgcn_mfma_f32_16x16x32_fp8_fp8(a, b, c, 0, 0, 0);
}
__device__ __forceinline__ f32x4 mfma_bf16(short8 a, short8 b, f32x4 c) {
  return __builtin_amdgcn_mfma_f32_16x16x32_bf16(a, b, c, 0, 0, 0);
}

// ------------------------------------------------------------ prep (merged) --
// Block roles: [0,1024) kv | [1024,1280) fold_wiho | [1280,1568) convert |
// [1568,1603) fold_wq3b. All independent -> concurrent in one launch.
// K8[b][m][128] fp8; V8[b][d][512] fp8 (transposed, m-permuted within each
// 32-token chunk: slot s holds token pi(s), pi(8q+j)=4q+j (j<4) else
// 16+4q+(j-4)).
__global__ __launch_bounds__(256) void prep_kernel(
    const float* __restrict__ emb, const float* __restrict__ wk,
    const float* __restrict__ bk, const float* __restrict__ wv,
    const float* __restrict__ bv,
    const float* __restrict__ w2, const float* __restrict__ whh,
    const float* __restrict__ wih, const float* __restrict__ wo,
    const float* __restrict__ wq, const float* __restrict__ w3,
    const float* __restrict__ b3, const float* __restrict__ bq,
    const float* __restrict__ bo, const float* __restrict__ bih,
    const float* __restrict__ bhh,
    unsigned char* __restrict__ K8, unsigned char* __restrict__ V8,
    unsigned short* __restrict__ W2, unsigned short* __restrict__ WHH,
    unsigned short* __restrict__ WIHO, unsigned short* __restrict__ WQ3,
    float* __restrict__ B4p, float* __restrict__ BQ3S) {
  extern __shared__ char smem[];
  const int tid = threadIdx.x;
  const int blk = blockIdx.x;

  if (blk < 1024) {  // ---- kv role ----
    float* s_e = (float*)smem;            // [64][129]
    float* s_w = (float*)(smem + 33024);  // [128][129]
    const int b = blk >> 3;
    const int m0 = (blk & 7) * 64;

    for (int i = tid; i < 8192; i += 256) {
      int row = i >> 7, col = i & 127;
      s_e[row * 129 + col] = emb[(size_t)(b * 512 + m0 + row) * 128 + col];
    }
    for (int i = tid; i < 16384; i += 256) {
      int row = i >> 7, col = i & 127;
      s_w[row * 129 + col] = wk[i];
    }
    __syncthreads();
    {  // K rows -> fp8
      const int dg = tid & 31, rg = tid >> 5;
      float acc[8][4];
#pragma unroll
      for (int rr = 0; rr < 8; ++rr)
#pragma unroll
        for (int j = 0; j < 4; ++j) acc[rr][j] = 0.f;
      for (int k = 0; k < 128; ++k) {
        float e[8];
#pragma unroll
        for (int rr = 0; rr < 8; ++rr) e[rr] = s_e[(rg * 8 + rr) * 129 + k];
#pragma unroll
        for (int j = 0; j < 4; ++j) {
          float w = s_w[(dg * 4 + j) * 129 + k];
#pragma unroll
          for (int rr = 0; rr < 8; ++rr) acc[rr][j] = fmaf(e[rr], w, acc[rr][j]);
        }
      }
#pragma unroll
      for (int rr = 0; rr < 8; ++rr)
#pragma unroll
        for (int j = 0; j < 4; ++j) {
          int d = dg * 4 + j;
          K8[(size_t)(b * 512 + m0 + rg * 8 + rr) * 128 + d] =
              f2fp8(acc[rr][j] + bk[d]);
        }
    }
    __syncthreads();
    for (int i = tid; i < 16384; i += 256) {
      int row = i >> 7, col = i & 127;
      s_w[row * 129 + col] = wv[i];
    }
    __syncthreads();
    {  // V transposed + m-permuted -> fp8
      const int r = tid & 63, dg = tid >> 6;
      float acc[32];
#pragma unroll
      for (int j = 0; j < 32; ++j) acc[j] = 0.f;
      for (int k = 0; k < 128; ++k) {
        float e = s_e[r * 129 + k];
#pragma unroll
        for (int j = 0; j < 32; ++j)
          acc[j] = fmaf(e, s_w[(dg * 32 + j) * 129 + k], acc[j]);
      }
      const int m = m0 + r;
      const int ml = m & 31;
      const int sperm = (ml < 16) ? (((ml >> 2) << 3) | (ml & 3))
                                  : ((((ml - 16) >> 2) << 3) | ((ml - 16) & 3) | 4);
      const int mpos = (m & ~31) | sperm;
#pragma unroll
      for (int j = 0; j < 32; ++j) {
        int d = dg * 32 + j;
        V8[(size_t)(b * 128 + d) * 512 + mpos] = f2fp8(acc[j] + bv[d]);
      }
    }
  } else if (blk < 1280) {  // ---- fold WIHO: WIHO[r][d] = wih@wo (bf16) ----
    int i = (blk - 1024) * 256 + tid;  // 65536
    int r = i >> 7, d = i & 127;
    float acc = 0.f;
    for (int n = 0; n < 128; ++n)
      acc = fmaf(wih[r * 128 + n], wo[n * 128 + d], acc);
    WIHO[i] = f2bf(acc);
  } else if (blk < 1568) {  // ---- convert W2 + WHH -> bf16 ----
    int i = (blk - 1280) * 256 + tid;
    if (i < 8192) W2[i] = f2bf(w2[i]);
    else if (i < 73728) WHH[i - 8192] = f2bf(whh[i - 8192]);
  } else {  // ---- fold WQ3 + biases ----
    int i = (blk - 1568) * 256 + tid;
    if (i < 8192) {
      int n = i >> 6, k = i & 63;
      float acc = 0.f;
      for (int j = 0; j < 128; ++j) acc = fmaf(wq[n * 128 + j], w3[j * 64 + k], acc);
      WQ3[i] = f2bf(acc * QSCALE);
    } else if (i < 8704) {
      int r = i - 8192;
      float acc = bih[r] + bhh[r];
      for (int n = 0; n < 128; ++n) acc = fmaf(wih[r * 128 + n], bo[n], acc);
      B4p[r] = acc;
    } else if (i < 8832) {
      int n = i - 8704;
      float acc = bq[n];
      for (int j = 0; j < 128; ++j) acc = fmaf(wq[n * 128 + j], b3[j], acc);
      BQ3S[n] = acc * QSCALE;
    }
  }
}

// ---------------------------------------------------------------- decoder ----
// grid 256 = 128 b x 2 agent-halves (32 agents). 512 threads = 8 waves.
// LDS (162560 B, 1 block/CU):
//   sK    @0      fp8 [512][128] XOR-swz  65536   (persistent)
//   sV    @65536  fp8 [128][512] XOR-swz  65536   (persistent, transposed+pi)
//   bufA  @131072 u16 [32][136]            8704   (h1 | qf8 bytes [32][136])
//   bufB  @139776 u16 [32][136]            8704   (o)
//   s_h   @148480 u16 [32][136]            8704
//   zone  @157184 h2 u16 [32][72]          4608
//   maskb @162048 u8 [512]                  512
// Per-step barriers (4): P1(+s_h prefetch)|P3+P4|P6|P7+P0.
__global__ __launch_bounds__(512, 2) void decoder_kernel(
    const float* __restrict__ cf, const int* __restrict__ cav,
    const float* __restrict__ hid,
    const float* __restrict__ ctx, const int* __restrict__ mav,
    const int* __restrict__ ntp,
    const float* __restrict__ w1, const float* __restrict__ b1,
    const float* __restrict__ b2,
    const unsigned char* __restrict__ K8, const unsigned char* __restrict__ V8,
    const unsigned short* __restrict__ W2, const unsigned short* __restrict__ WQ3,
    const unsigned short* __restrict__ WIHO, const unsigned short* __restrict__ WHH,
    const float* __restrict__ B4p, const float* __restrict__ BQ3S,
    const float* __restrict__ lnw, const float* __restrict__ lnb,
    float* __restrict__ out) {
  extern __shared__ char smem[];
  unsigned short* s_bufA = (unsigned short*)(smem + 131072);
  unsigned short* s_bufB = (unsigned short*)(smem + 139776);
  unsigned short* s_h = (unsigned short*)(smem + 148480);
  unsigned short* s_h2 = (unsigned short*)(smem + 157184);
  unsigned char* s_maskb = (unsigned char*)(smem + 162048);

  const int tid = threadIdx.x;
  const int wave = tid >> 6;
  const int lane = tid & 63;
  const int quad = lane >> 4;
  const int l16 = lane & 15;

  const int b = blockIdx.x & 127;
  const int a0 = (blockIdx.x >> 7) * 32;
  const int T = *ntp;
  const f32x4 zero4 = {0.f, 0.f, 0.f, 0.f};
  const long kOnes = 0x3838383838383838L;  // fp8 e4m3 1.0 x8

  // ---- preload persistent K/V into LDS with XOR swizzle ----
  {
    const unsigned long long* Kg = (const unsigned long long*)(K8 + (size_t)b * 65536);
    for (int i = tid; i < 8192; i += 512) {
      int tok = i >> 4, seg = i & 15;
      *(unsigned long long*)(smem + tok * 128 + ((seg * 8) ^ ((tok & 15) * 8))) =
          Kg[(size_t)tok * 16 + seg];
    }
    const unsigned long long* Vg = (const unsigned long long*)(V8 + (size_t)b * 65536);
    for (int i = tid; i < 8192; i += 512) {
      int d = i >> 6, seg = i & 63;
      *(unsigned long long*)(smem + 65536 + d * 512 + ((seg * 8) ^ ((d & 15) * 8))) =
          Vg[(size_t)d * 64 + seg];
    }
  }
  // ---- init ----
  s_maskb[tid] = mav[b * 512 + tid] ? 1 : 0;
  {  // h0 (32 agents x 128 -> 8 per thread)
    int idx = tid * 8;
    int a = idx >> 7, n0 = idx & 127;
    const float* hp = hid + (size_t)(b * 64 + a0 + a) * 128 + n0;
    short8 v;
#pragma unroll
    for (int j = 0; j < 8; ++j) v[j] = (short)f2bf(hp[j]);
    *(short8*)(s_h + a * 136 + n0) = v;
  }
  float c_reg[2][4], avl[2][4];
#pragma unroll
  for (int mt = 0; mt < 2; ++mt)
#pragma unroll
    for (int r = 0; r < 4; ++r) {
      int a = mt * 16 + quad * 4 + r;
      c_reg[mt][r] = ctx[(size_t)(b * 64 + a0 + a) * 128 + wave * 16 + l16];
      avl[mt][r] = (cav[b * 64 + a0 + a] != 0) ? 1.f : 0.f;
    }

  // ---- persistent register-cached weights (step-invariant) ----
  const int wrow = wave * 16 + l16;
  short8 rIH[4][4], rHH[4][4];
#pragma unroll
  for (int kt = 0; kt < 4; ++kt)
#pragma unroll
    for (int g = 0; g < 4; ++g) {
      rIH[kt][g] = *(const short8*)(WIHO + ((g * 128 + wrow) * 128 + kt * 32 + quad * 8));
      rHH[kt][g] = *(const short8*)(WHH + ((g * 128 + wrow) * 128 + kt * 32 + quad * 8));
    }
  short8 rWQ3[2];
#pragma unroll
  for (int kt = 0; kt < 2; ++kt)
    rWQ3[kt] = *(const short8*)(WQ3 + (wrow * 64 + kt * 32 + quad * 8));
  float rB4[4];
#pragma unroll
  for (int g = 0; g < 4; ++g) rB4[g] = B4p[g * 128 + wrow];
  const float rBQ3 = BQ3S[wrow];
  const float rB2 = b2[(wave & 3) * 16 + l16];

  // ---- fused-P7/P0 per-thread constants + register state ----
  const int p7_o = tid >> 3, p7_sub = tid & 7;
  const int p7_a = p7_o >> 1, p7_oi = p7_o & 1;
  const float mylnb = lnb[p7_oi];
  float myst = cf[(size_t)(b * 64 + a0 + p7_a) * 2 + p7_oi];

  __syncthreads();

  // per-lane mask flags: bit i set when token i*16+l16 is NOT available.
  unsigned mflags = 0;
#pragma unroll
  for (int i = 0; i < 32; ++i)
    if (!s_maskb[i * 16 + l16]) mflags |= (1u << i);

  // ---- initial h1 from initial state (P0 stand-alone) ----
  {
    float other = __shfl_xor(myst, 8);
    float st0 = p7_oi ? other : myst;
    float st1 = p7_oi ? myst : other;
    int a = tid >> 4, n0 = (tid & 15) * 8;
    const float* wp = w1 + n0 * 2;
    const float* bp = b1 + n0;
    short8 v;
#pragma unroll
    for (int j = 0; j < 8; ++j) {
      float x = fmaf(wp[j * 2], st0, fmaf(wp[j * 2 + 1], st1, bp[j]));
      v[j] = (short)f2bf(fmaxf(x, 0.f));
    }
    *(short8*)(s_bufA + a * 136 + n0) = v;
  }
  __syncthreads();

#pragma unroll 1
  for (int t = 0; t < T; ++t) {
    // ---- s_h(t) prefetch (HH A-frags + old-h) — issued in P1 phase.
    // The P1-end barrier drain completes these block-wide BEFORE any P6
    // write, which is what lets P6 run without its mid-barrier.
    short8 rHa[4][2];
    float hoF[2][4];
#pragma unroll
    for (int kt = 0; kt < 4; ++kt)
#pragma unroll
      for (int mt = 0; mt < 2; ++mt)
        rHa[kt][mt] = *(const short8*)(s_h + (mt * 16 + l16) * 136 + kt * 32 + quad * 8);
#pragma unroll
    for (int mt = 0; mt < 2; ++mt)
#pragma unroll
      for (int r = 0; r < 4; ++r) {
        union { unsigned int u; float f; } ho;
        ho.u = ((unsigned int)s_h[(mt * 16 + quad * 4 + r) * 136 + wave * 16 + l16]) << 16;
        hoF[mt][r] = ho.f;
      }

    // ---- P1: h2 = relu(h1 @ w2^T + b2)  M32 N64 K128 -> zone ----
    {
      int mt = wave >> 2, nt = wave & 3;
      f32x4 acc = splat4(rB2);
#pragma unroll
      for (int kt = 0; kt < 4; ++kt) {
        short8 a8 = *(const short8*)(s_bufA + (mt * 16 + l16) * 136 + kt * 32 + quad * 8);
        short8 b8 = *(const short8*)(W2 + ((nt * 16 + l16) * 128 + kt * 32 + quad * 8));
        acc = mfma_bf16(a8, b8, acc);
      }
#pragma unroll
      for (int r = 0; r < 4; ++r)
        s_h2[(mt * 16 + quad * 4 + r) * 72 + nt * 16 + l16] = f2bf(fmaxf(acc[r], 0.f));
    }
    __syncthreads();

    // ---- P3: q = h2 @ WQ3^T + bq3 -> fp8 in bufA bytes (h1 dead) ----
    // wave nt==h produces exactly head h's q-columns -> no barrier before P4.
    unsigned char* s_q8 = (unsigned char*)s_bufA;
    {
#pragma unroll
      for (int mt = 0; mt < 2; ++mt) {
        f32x4 acc = splat4(rBQ3);
#pragma unroll
        for (int kt = 0; kt < 2; ++kt) {
          short8 a8 = *(const short8*)(s_h2 + (mt * 16 + l16) * 72 + kt * 32 + quad * 8);
          acc = mfma_bf16(a8, rWQ3[kt], acc);
        }
#pragma unroll
        for (int r = 0; r < 4; ++r)
          s_q8[(mt * 16 + quad * 4 + r) * 136 + wave * 16 + l16] = f2fp8(acc[r]);
      }
    }
    __asm__ volatile("s_waitcnt lgkmcnt(0)" ::: "memory");
    __builtin_amdgcn_sched_barrier(0);

    // ---- P4: attention — swapped-operand MFMA, in-register P, 2-stage
    // pipeline: S-MFMAs for chunk c+1 issue before exp/pack/PV of chunk c. ----
    {
      const int h = wave;
      const char* sKb = (const char*)smem;
      const char* sVrow = (const char*)(smem + 65536) + (h * 16 + l16) * 512;
      long qA[2];
#pragma unroll
      for (int mt = 0; mt < 2; ++mt)
        qA[mt] = (quad < 2)
                     ? *(const long*)(s_q8 + (mt * 16 + l16) * 136 + h * 16 + quad * 8)
                     : (quad == 2 ? 0xF8L : 0L);  // byte0 = fp8 -256
      const int koff = (h * 16 + quad * 8) ^ (l16 * 8);
      auto ldK = [&](int c, long& k0, long& k1) {
        if (quad < 2) {
          k0 = *(const long*)(sKb + (size_t)(c * 32 + l16) * 128 + koff);
          k1 = *(const long*)(sKb + (size_t)(c * 32 + 16 + l16) * 128 + koff);
        } else if (quad == 2) {
          k0 = ((mflags >> (c * 2)) & 1u) ? 0x38L : 0L;      // fp8 1.0 flag
          k1 = ((mflags >> (c * 2 + 1)) & 1u) ? 0x38L : 0L;
        } else { k0 = 0L; k1 = 0L; }
      };
      f32x4 O[2], L4[2];
      O[0] = zero4; O[1] = zero4; L4[0] = zero4; L4[1] = zero4;
      long kS0, kS1, kP0, kP1;
      ldK(0, kS0, kS1);
      ldK(1, kP0, kP1);
      long vAc = *(const long*)(sVrow + ((quad * 8) ^ (l16 * 8)));
      f32x4 Sc[2][2];
      Sc[0][0] = mfma_fp8(kS0, qA[0], zero4);
      Sc[0][1] = mfma_fp8(kS0, qA[1], zero4);
      Sc[1][0] = mfma_fp8(kS1, qA[0], zero4);
      Sc[1][1] = mfma_fp8(kS1, qA[1], zero4);
#pragma unroll 2
      for (int c = 0; c < 16; ++c) {
        long kN0 = 0L, kN1 = 0L, vAn = 0L;
        if (c < 14) ldK(c + 2, kN0, kN1);
        if (c < 15)
          vAn = *(const long*)(sVrow + (((c + 1) * 32 + quad * 8) ^ (l16 * 8)));
        f32x4 Sn[2][2];
        if (c < 15) {  // S for chunk c+1 (kB loaded 2 iters ago -> ready)
          Sn[0][0] = mfma_fp8(kP0, qA[0], zero4);
          Sn[0][1] = mfma_fp8(kP0, qA[1], zero4);
          Sn[1][0] = mfma_fp8(kP1, qA[0], zero4);
          Sn[1][1] = mfma_fp8(kP1, qA[1], zero4);
        }
        // exp/pack/PV for chunk c (Sc computed last iter -> latency hidden)
#pragma unroll
        for (int mt = 0; mt < 2; ++mt) {
          unsigned w0 = (unsigned)__builtin_amdgcn_cvt_pk_fp8_f32(
              fexp2(Sc[0][mt][0]), fexp2(Sc[0][mt][1]), 0, false);
          w0 = (unsigned)__builtin_amdgcn_cvt_pk_fp8_f32(
              fexp2(Sc[0][mt][2]), fexp2(Sc[0][mt][3]), (int)w0, true);
          unsigned w1v = (unsigned)__builtin_amdgcn_cvt_pk_fp8_f32(
              fexp2(Sc[1][mt][0]), fexp2(Sc[1][mt][1]), 0, false);
          w1v = (unsigned)__builtin_amdgcn_cvt_pk_fp8_f32(
              fexp2(Sc[1][mt][2]), fexp2(Sc[1][mt][3]), (int)w1v, true);
          long pB = (long)(((unsigned long long)w1v << 32) | (unsigned long long)w0);
          O[mt] = mfma_fp8(vAc, pB, O[mt]);     // O^T: rows d-local, cols a
          L4[mt] = mfma_fp8(kOnes, pB, L4[mt]);
        }
        // rotate pipeline registers
        Sc[0][0] = Sn[0][0]; Sc[0][1] = Sn[0][1];
        Sc[1][0] = Sn[1][0]; Sc[1][1] = Sn[1][1];
        kP0 = kN0; kP1 = kN1; vAc = vAn;
      }
      // o -> bufB; O^T lane layout: d = h*16+quad*4+r, a = mt*16+l16
#pragma unroll
      for (int mt = 0; mt < 2; ++mt) {
        unsigned long long ow = 0;
#pragma unroll
        for (int r = 0; r < 4; ++r) {
          float o_r = O[mt][r] * frcp(L4[mt][r]);
          ow |= (unsigned long long)f2bf(o_r) << (16 * r);
        }
        *(unsigned long long*)(s_bufB + (mt * 16 + l16) * 136 + h * 16 + quad * 4) = ow;
      }
    }
    __syncthreads();

    // ---- P6: LSTM gates (o from LDS, h from prefetched regs) — no
    // mid-barrier: all s_h(t) reads completed at the P1-end barrier. ----
    {
      const int ni = wave;
      short8 oa8[4][2];
#pragma unroll
      for (int kt = 0; kt < 4; ++kt)
#pragma unroll
        for (int mt = 0; mt < 2; ++mt)
          oa8[kt][mt] = *(const short8*)(s_bufB + (mt * 16 + l16) * 136 + kt * 32 + quad * 8);
      f32x4 gi[2], gf[2], gg[2], go[2];
#pragma unroll
      for (int mt = 0; mt < 2; ++mt) {
        gi[mt] = splat4(rB4[0]);
        gf[mt] = splat4(rB4[1]);
        gg[mt] = splat4(rB4[2]);
        go[mt] = splat4(rB4[3]);
      }
#pragma unroll
      for (int kt = 0; kt < 4; ++kt)
#pragma unroll
        for (int mt = 0; mt < 2; ++mt) {
          gi[mt] = mfma_bf16(oa8[kt][mt], rIH[kt][0], gi[mt]);
          gf[mt] = mfma_bf16(oa8[kt][mt], rIH[kt][1], gf[mt]);
          gg[mt] = mfma_bf16(oa8[kt][mt], rIH[kt][2], gg[mt]);
          go[mt] = mfma_bf16(oa8[kt][mt], rIH[kt][3], go[mt]);
        }
#pragma unroll
      for (int kt = 0; kt < 4; ++kt)
#pragma unroll
        for (int mt = 0; mt < 2; ++mt) {
          gi[mt] = mfma_bf16(rHa[kt][mt], rHH[kt][0], gi[mt]);
          gf[mt] = mfma_bf16(rHa[kt][mt], rHH[kt][1], gf[mt]);
          gg[mt] = mfma_bf16(rHa[kt][mt], rHH[kt][2], gg[mt]);
          go[mt] = mfma_bf16(rHa[kt][mt], rHH[kt][3], go[mt]);
        }
#pragma unroll
      for (int mt = 0; mt < 2; ++mt)
#pragma unroll
        for (int r = 0; r < 4; ++r) {
          float iv = sigm(gi[mt][r]);
          float fv = sigm(gf[mt][r]);
          float gv = tanh_f(gg[mt][r]);
          float ov = sigm(go[mt][r]);
          float cn = fmaf(fv, c_reg[mt][r], iv * gv);
          float hv = ov * tanh_f(cn);
          float av = avl[mt][r];
          c_reg[mt][r] = av * cn + (1.f - av) * c_reg[mt][r];
          float hn = av * hv + (1.f - av) * hoF[mt][r];
          int arow = mt * 16 + quad * 4 + r;
          s_h[arow * 136 + ni * 16 + l16] = f2bf(hn);
        }
    }
    __syncthreads();

    // ---- P7+P0 fused: state += h @ lin_w^T + lin_b; emit; next h1 ----
    {
      const unsigned short* hp = s_h + p7_a * 136 + p7_sub * 16;
      const float* lw = lnw + p7_oi * 128 + p7_sub * 16;
      short8 h0 = *(const short8*)hp;
      short8 h1 = *(const short8*)(hp + 8);
      float acc = 0.f;
#pragma unroll
      for (int k = 0; k < 8; ++k) {
        union { unsigned int u; float f; } hv;
        hv.u = ((unsigned int)(unsigned short)h0[k]) << 16;
        acc = fmaf(hv.f, lw[k], acc);
      }
#pragma unroll
      for (int k = 0; k < 8; ++k) {
        union { unsigned int u; float f; } hv;
        hv.u = ((unsigned int)(unsigned short)h1[k]) << 16;
        acc = fmaf(hv.f, lw[8 + k], acc);
      }
      acc += __shfl_xor(acc, 4);
      acc += __shfl_xor(acc, 2);
      acc += __shfl_xor(acc, 1);
      float ns = myst + acc + mylnb;
      myst = ns;
      if (p7_sub == 0)
        out[((size_t)(b * 64 + a0 + p7_a) * T + t) * 2 + p7_oi] = ns;
      // P0: h1(t+1) = relu(state @ w1^T + b1) -> bufA
      float other = __shfl_xor(ns, 8);
      float st0 = p7_oi ? other : ns;
      float st1 = p7_oi ? ns : other;
      int a = tid >> 4, n0 = (tid & 15) * 8;
      const float* wp = w1 + n0 * 2;
      const float* bp = b1 + n0;
      short8 v;
#pragma unroll
      for (int j = 0; j < 8; ++j) {
        float x = fmaf(wp[j * 2], st0, fmaf(wp[j * 2 + 1], st1, bp[j]));
        v[j] = (short)f2bf(fmaxf(x, 0.f));
      }
      *(short8*)(s_bufA + a * 136 + n0) = v;
    }
    __syncthreads();
  }
}

// ---------------------------------------------------------------- launch ----
extern "C" void kernel_launch(void* const* d_in, const int* in_sizes, int n_in,
                              void* d_out, int out_size, void* d_ws, size_t ws_size,
                              hipStream_t stream) {
  (void)in_sizes; (void)n_in; (void)out_size; (void)ws_size;
  const float* cf = (const float*)d_in[0];
  const int* cav = (const int*)d_in[1];
  const float* hid = (const float*)d_in[2];
  const float* ctx = (const float*)d_in[3];
  const float* emb = (const float*)d_in[4];
  const int* mav = (const int*)d_in[5];
  const int* ntp = (const int*)d_in[6];
  const float* w1 = (const float*)d_in[7];
  const float* b1 = (const float*)d_in[8];
  const float* w2 = (const float*)d_in[9];
  const float* b2 = (const float*)d_in[10];
  const float* w3 = (const float*)d_in[11];
  const float* b3 = (const float*)d_in[12];
  const float* wq = (const float*)d_in[13];
  const float* bq = (const float*)d_in[14];
  const float* wk = (const float*)d_in[15];
  const float* bk = (const float*)d_in[16];
  const float* wv = (const float*)d_in[17];
  const float* bv = (const float*)d_in[18];
  const float* wo = (const float*)d_in[19];
  const float* bo = (const float*)d_in[20];
  const float* wih = (const float*)d_in[21];  // w_ih
  const float* whh = (const float*)d_in[22];  // w_hh
  const float* bih = (const float*)d_in[23];  // b_ih
  const float* bhh = (const float*)d_in[24];  // b_hh
  const float* lnw = (const float*)d_in[25];
  const float* lnb = (const float*)d_in[26];

  char* ws = (char*)d_ws;
  unsigned char* K8 = (unsigned char*)(ws + 0);         // 8,388,608
  unsigned char* V8 = (unsigned char*)(ws + 8388608);   // 8,388,608
  unsigned short* W2s = (unsigned short*)(ws + 16777216);   // 16,384 B
  unsigned short* WQ3s = (unsigned short*)(ws + 16793600);  // 16,384 B
  unsigned short* WIHOs = (unsigned short*)(ws + 16809984); // 131,072 B
  unsigned short* WHHs = (unsigned short*)(ws + 16941056);  // 131,072 B
  float* B4p = (float*)(ws + 17072128);                     // 2,048 B
  float* BQ3S = (float*)(ws + 17074176);                    // 512 B

  (void)hipFuncSetAttribute((const void*)prep_kernel,
                            hipFuncAttributeMaxDynamicSharedMemorySize, 99072);
  (void)hipFuncSetAttribute((const void*)decoder_kernel,
                            hipFuncAttributeMaxDynamicSharedMemorySize, 162560);

  prep_kernel<<<1603, 256, 99072, stream>>>(
      emb, wk, bk, wv, bv, w2, whh, wih, wo, wq, w3, b3, bq, bo, bih, bhh,
      K8, V8, W2s, WHHs, WIHOs, WQ3s, B4p, BQ3S);
  decoder_kernel<<<256, 512, 162560, stream>>>(
      cf, cav, hid, ctx, mav, ntp, w1, b1, b2, K8, V8, W2s, WQ3s, WIHOs, WHHs,
      B4p, BQ3S, lnw, lnb, (float*)d_out);
}

// Round 7
// 1255.323 us; speedup vs baseline: 1.6927x; 1.6927x over previous
//
#include <hip/hip_runtime.h>
#include <cstdint>
#include <cstddef>

// Decoder_55654186222328 — MI355X, R15: R13 decoder (verbatim) + merged prep.
// R14 post-mortem (1007 -> 1888us): FETCH 23.7MB -> 3.8GB at fixed 128 VGPR.
// The added cross-phase live state (s_h prefetch regs + P4 2-stage pipeline +
// oa8 batch ≈ +110 VGPRs over the 128-reg weight cache) overflowed the
// allocator's budget -> scratch/remat global traffic inside the 80-step loop.
// Lesson: the register budget here is ~128 and everything past it becomes HBM
// traffic; pipelining must be added <=16 VGPRs at a time with FETCH watched.
// R15 reverts the decoder to R13's proven structure (5 barriers/step) and
// keeps only R14's independent win: the merged single prep kernel.
// 256 blocks (128 b x 2 agent halves of 32) x 512 threads, 1 block/CU,
// LDS 162560 B.

typedef short short8 __attribute__((ext_vector_type(8)));
typedef float f32x4 __attribute__((ext_vector_type(4)));

#define LOG2E 1.4426950408889634f
#define QSCALE 0.36067376022224085f /* log2(e)/4 */

__device__ __forceinline__ unsigned short f2bf(float f) {
  union { float f; unsigned int u; } v; v.f = f;
  unsigned int u = v.u;
  return (unsigned short)((u + 0x7fffu + ((u >> 16) & 1u)) >> 16);  // RNE
}
__device__ __forceinline__ float fexp2(float x) {
  return __builtin_amdgcn_exp2f(x);   // v_exp_f32, compiler-managed hazards
}
__device__ __forceinline__ float frcp(float x) {
  return __builtin_amdgcn_rcpf(x);    // v_rcp_f32, compiler-managed hazards
}
__device__ __forceinline__ float sigm(float x) {
  return frcp(1.f + fexp2(-LOG2E * x));
}
__device__ __forceinline__ float tanh_f(float x) {
  return 1.f - 2.f * frcp(1.f + fexp2(2.f * LOG2E * x));
}
__device__ __forceinline__ f32x4 splat4(float v) { f32x4 r = {v, v, v, v}; return r; }
__device__ __forceinline__ unsigned char f2fp8(float x) {
  return (unsigned char)__builtin_amdgcn_cvt_pk_fp8_f32(x, x, 0, false);
}
__device__ __forceinline__ f32x4 mfma_fp8(long a, long b, f32x4 c) {
  return __builtin_amdgcn_mfma_f32_16x16x32_fp8_fp8(a, b, c, 0, 0, 0);
}
__device__ __forceinline__ f32x4 mfma_bf16(short8 a, short8 b, f32x4 c) {
  return __builtin_amdgcn_mfma_f32_16x16x32_bf16(a, b, c, 0, 0, 0);
}

// ------------------------------------------------------------ prep (merged) --
// Block roles: [0,1024) kv | [1024,1280) fold_wiho | [1280,1568) convert |
// [1568,1603) fold_wq3b. All independent -> concurrent in one launch.
// K8[b][m][128] fp8; V8[b][d][512] fp8 (transposed, m-permuted within each
// 32-token chunk: slot s holds token pi(s), pi(8q+j)=4q+j (j<4) else
// 16+4q+(j-4)).
__global__ __launch_bounds__(256) void prep_kernel(
    const float* __restrict__ emb, const float* __restrict__ wk,
    const float* __restrict__ bk, const float* __restrict__ wv,
    const float* __restrict__ bv,
    const float* __restrict__ w2, const float* __restrict__ whh,
    const float* __restrict__ wih, const float* __restrict__ wo,
    const float* __restrict__ wq, const float* __restrict__ w3,
    const float* __restrict__ b3, const float* __restrict__ bq,
    const float* __restrict__ bo, const float* __restrict__ bih,
    const float* __restrict__ bhh,
    unsigned char* __restrict__ K8, unsigned char* __restrict__ V8,
    unsigned short* __restrict__ W2, unsigned short* __restrict__ WHH,
    unsigned short* __restrict__ WIHO, unsigned short* __restrict__ WQ3,
    float* __restrict__ B4p, float* __restrict__ BQ3S) {
  extern __shared__ char smem[];
  const int tid = threadIdx.x;
  const int blk = blockIdx.x;

  if (blk < 1024) {  // ---- kv role ----
    float* s_e = (float*)smem;            // [64][129]
    float* s_w = (float*)(smem + 33024);  // [128][129]
    const int b = blk >> 3;
    const int m0 = (blk & 7) * 64;

    for (int i = tid; i < 8192; i += 256) {
      int row = i >> 7, col = i & 127;
      s_e[row * 129 + col] = emb[(size_t)(b * 512 + m0 + row) * 128 + col];
    }
    for (int i = tid; i < 16384; i += 256) {
      int row = i >> 7, col = i & 127;
      s_w[row * 129 + col] = wk[i];
    }
    __syncthreads();
    {  // K rows -> fp8
      const int dg = tid & 31, rg = tid >> 5;
      float acc[8][4];
#pragma unroll
      for (int rr = 0; rr < 8; ++rr)
#pragma unroll
        for (int j = 0; j < 4; ++j) acc[rr][j] = 0.f;
      for (int k = 0; k < 128; ++k) {
        float e[8];
#pragma unroll
        for (int rr = 0; rr < 8; ++rr) e[rr] = s_e[(rg * 8 + rr) * 129 + k];
#pragma unroll
        for (int j = 0; j < 4; ++j) {
          float w = s_w[(dg * 4 + j) * 129 + k];
#pragma unroll
          for (int rr = 0; rr < 8; ++rr) acc[rr][j] = fmaf(e[rr], w, acc[rr][j]);
        }
      }
#pragma unroll
      for (int rr = 0; rr < 8; ++rr)
#pragma unroll
        for (int j = 0; j < 4; ++j) {
          int d = dg * 4 + j;
          K8[(size_t)(b * 512 + m0 + rg * 8 + rr) * 128 + d] =
              f2fp8(acc[rr][j] + bk[d]);
        }
    }
    __syncthreads();
    for (int i = tid; i < 16384; i += 256) {
      int row = i >> 7, col = i & 127;
      s_w[row * 129 + col] = wv[i];
    }
    __syncthreads();
    {  // V transposed + m-permuted -> fp8
      const int r = tid & 63, dg = tid >> 6;
      float acc[32];
#pragma unroll
      for (int j = 0; j < 32; ++j) acc[j] = 0.f;
      for (int k = 0; k < 128; ++k) {
        float e = s_e[r * 129 + k];
#pragma unroll
        for (int j = 0; j < 32; ++j)
          acc[j] = fmaf(e, s_w[(dg * 32 + j) * 129 + k], acc[j]);
      }
      const int m = m0 + r;
      const int ml = m & 31;
      const int sperm = (ml < 16) ? (((ml >> 2) << 3) | (ml & 3))
                                  : ((((ml - 16) >> 2) << 3) | ((ml - 16) & 3) | 4);
      const int mpos = (m & ~31) | sperm;
#pragma unroll
      for (int j = 0; j < 32; ++j) {
        int d = dg * 32 + j;
        V8[(size_t)(b * 128 + d) * 512 + mpos] = f2fp8(acc[j] + bv[d]);
      }
    }
  } else if (blk < 1280) {  // ---- fold WIHO: WIHO[r][d] = wih@wo (bf16) ----
    int i = (blk - 1024) * 256 + tid;  // 65536
    int r = i >> 7, d = i & 127;
    float acc = 0.f;
    for (int n = 0; n < 128; ++n)
      acc = fmaf(wih[r * 128 + n], wo[n * 128 + d], acc);
    WIHO[i] = f2bf(acc);
  } else if (blk < 1568) {  // ---- convert W2 + WHH -> bf16 ----
    int i = (blk - 1280) * 256 + tid;
    if (i < 8192) W2[i] = f2bf(w2[i]);
    else if (i < 73728) WHH[i - 8192] = f2bf(whh[i - 8192]);
  } else {  // ---- fold WQ3 + biases ----
    int i = (blk - 1568) * 256 + tid;
    if (i < 8192) {
      int n = i >> 6, k = i & 63;
      float acc = 0.f;
      for (int j = 0; j < 128; ++j) acc = fmaf(wq[n * 128 + j], w3[j * 64 + k], acc);
      WQ3[i] = f2bf(acc * QSCALE);
    } else if (i < 8704) {
      int r = i - 8192;
      float acc = bih[r] + bhh[r];
      for (int n = 0; n < 128; ++n) acc = fmaf(wih[r * 128 + n], bo[n], acc);
      B4p[r] = acc;
    } else if (i < 8832) {
      int n = i - 8704;
      float acc = bq[n];
      for (int j = 0; j < 128; ++j) acc = fmaf(wq[n * 128 + j], b3[j], acc);
      BQ3S[n] = acc * QSCALE;
    }
  }
}

// ---------------------------------------------------------------- decoder ----
// grid 256 = 128 b x 2 agent-halves (32 agents). 512 threads = 8 waves.
// LDS (162560 B, 1 block/CU):
//   sK    @0      fp8 [512][128] XOR-swz  65536   (persistent)
//   sV    @65536  fp8 [128][512] XOR-swz  65536   (persistent, transposed+pi)
//   bufA  @131072 u16 [32][136]            8704   (h1 | qf8 bytes [32][136])
//   bufB  @139776 u16 [32][136]            8704   (o)
//   s_h   @148480 u16 [32][136]            8704
//   zone  @157184 h2 u16 [32][72]          4608
//   maskb @162048 u8 [512]                  512
// Per-step barriers (5): P1|P3+P4|P6c|P6w|P7+P0.  (R13 structure, proven.)
__global__ __launch_bounds__(512, 2) void decoder_kernel(
    const float* __restrict__ cf, const int* __restrict__ cav,
    const float* __restrict__ hid,
    const float* __restrict__ ctx, const int* __restrict__ mav,
    const int* __restrict__ ntp,
    const float* __restrict__ w1, const float* __restrict__ b1,
    const float* __restrict__ b2,
    const unsigned char* __restrict__ K8, const unsigned char* __restrict__ V8,
    const unsigned short* __restrict__ W2, const unsigned short* __restrict__ WQ3,
    const unsigned short* __restrict__ WIHO, const unsigned short* __restrict__ WHH,
    const float* __restrict__ B4p, const float* __restrict__ BQ3S,
    const float* __restrict__ lnw, const float* __restrict__ lnb,
    float* __restrict__ out) {
  extern __shared__ char smem[];
  unsigned short* s_bufA = (unsigned short*)(smem + 131072);
  unsigned short* s_bufB = (unsigned short*)(smem + 139776);
  unsigned short* s_h = (unsigned short*)(smem + 148480);
  unsigned short* s_h2 = (unsigned short*)(smem + 157184);
  unsigned char* s_maskb = (unsigned char*)(smem + 162048);

  const int tid = threadIdx.x;
  const int wave = tid >> 6;
  const int lane = tid & 63;
  const int quad = lane >> 4;
  const int l16 = lane & 15;

  const int b = blockIdx.x & 127;
  const int a0 = (blockIdx.x >> 7) * 32;
  const int T = *ntp;
  const f32x4 zero4 = {0.f, 0.f, 0.f, 0.f};
  const long kOnes = 0x3838383838383838L;  // fp8 e4m3 1.0 x8

  // ---- preload persistent K/V into LDS with XOR swizzle ----
  {
    const unsigned long long* Kg = (const unsigned long long*)(K8 + (size_t)b * 65536);
    for (int i = tid; i < 8192; i += 512) {
      int tok = i >> 4, seg = i & 15;
      *(unsigned long long*)(smem + tok * 128 + ((seg * 8) ^ ((tok & 15) * 8))) =
          Kg[(size_t)tok * 16 + seg];
    }
    const unsigned long long* Vg = (const unsigned long long*)(V8 + (size_t)b * 65536);
    for (int i = tid; i < 8192; i += 512) {
      int d = i >> 6, seg = i & 63;
      *(unsigned long long*)(smem + 65536 + d * 512 + ((seg * 8) ^ ((d & 15) * 8))) =
          Vg[(size_t)d * 64 + seg];
    }
  }
  // ---- init ----
  s_maskb[tid] = mav[b * 512 + tid] ? 1 : 0;
  {  // h0 (32 agents x 128 -> 8 per thread)
    int idx = tid * 8;
    int a = idx >> 7, n0 = idx & 127;
    const float* hp = hid + (size_t)(b * 64 + a0 + a) * 128 + n0;
    short8 v;
#pragma unroll
    for (int j = 0; j < 8; ++j) v[j] = (short)f2bf(hp[j]);
    *(short8*)(s_h + a * 136 + n0) = v;
  }
  float c_reg[2][4], avl[2][4];
#pragma unroll
  for (int mt = 0; mt < 2; ++mt)
#pragma unroll
    for (int r = 0; r < 4; ++r) {
      int a = mt * 16 + quad * 4 + r;
      c_reg[mt][r] = ctx[(size_t)(b * 64 + a0 + a) * 128 + wave * 16 + l16];
      avl[mt][r] = (cav[b * 64 + a0 + a] != 0) ? 1.f : 0.f;
    }

  // ---- persistent register-cached weights (step-invariant) ----
  const int wrow = wave * 16 + l16;
  short8 rIH[4][4], rHH[4][4];
#pragma unroll
  for (int kt = 0; kt < 4; ++kt)
#pragma unroll
    for (int g = 0; g < 4; ++g) {
      rIH[kt][g] = *(const short8*)(WIHO + ((g * 128 + wrow) * 128 + kt * 32 + quad * 8));
      rHH[kt][g] = *(const short8*)(WHH + ((g * 128 + wrow) * 128 + kt * 32 + quad * 8));
    }
  short8 rWQ3[2];
#pragma unroll
  for (int kt = 0; kt < 2; ++kt)
    rWQ3[kt] = *(const short8*)(WQ3 + (wrow * 64 + kt * 32 + quad * 8));
  float rB4[4];
#pragma unroll
  for (int g = 0; g < 4; ++g) rB4[g] = B4p[g * 128 + wrow];
  const float rBQ3 = BQ3S[wrow];
  const float rB2 = b2[(wave & 3) * 16 + l16];

  // ---- fused-P7/P0 per-thread constants + register state ----
  const int p7_o = tid >> 3, p7_sub = tid & 7;
  const int p7_a = p7_o >> 1, p7_oi = p7_o & 1;
  const float mylnb = lnb[p7_oi];
  float myst = cf[(size_t)(b * 64 + a0 + p7_a) * 2 + p7_oi];

  __syncthreads();

  // per-lane mask flags: bit i set when token i*16+l16 is NOT available.
  unsigned mflags = 0;
#pragma unroll
  for (int i = 0; i < 32; ++i)
    if (!s_maskb[i * 16 + l16]) mflags |= (1u << i);

  // ---- initial h1 from initial state (P0 stand-alone) ----
  {
    float other = __shfl_xor(myst, 8);
    float st0 = p7_oi ? other : myst;
    float st1 = p7_oi ? myst : other;
    int a = tid >> 4, n0 = (tid & 15) * 8;
    const float* wp = w1 + n0 * 2;
    const float* bp = b1 + n0;
    short8 v;
#pragma unroll
    for (int j = 0; j < 8; ++j) {
      float x = fmaf(wp[j * 2], st0, fmaf(wp[j * 2 + 1], st1, bp[j]));
      v[j] = (short)f2bf(fmaxf(x, 0.f));
    }
    *(short8*)(s_bufA + a * 136 + n0) = v;
  }
  __syncthreads();

#pragma unroll 1
  for (int t = 0; t < T; ++t) {
    // ---- P1: h2 = relu(h1 @ w2^T + b2)  M32 N64 K128 -> zone ----
    {
      int mt = wave >> 2, nt = wave & 3;
      f32x4 acc = splat4(rB2);
#pragma unroll
      for (int kt = 0; kt < 4; ++kt) {
        short8 a8 = *(const short8*)(s_bufA + (mt * 16 + l16) * 136 + kt * 32 + quad * 8);
        short8 b8 = *(const short8*)(W2 + ((nt * 16 + l16) * 128 + kt * 32 + quad * 8));
        acc = mfma_bf16(a8, b8, acc);
      }
#pragma unroll
      for (int r = 0; r < 4; ++r)
        s_h2[(mt * 16 + quad * 4 + r) * 72 + nt * 16 + l16] = f2bf(fmaxf(acc[r], 0.f));
    }
    __syncthreads();

    // ---- P3: q = h2 @ WQ3^T + bq3 -> fp8 in bufA bytes (h1 dead) ----
    // wave nt==h produces exactly head h's q-columns -> no barrier before P4.
    unsigned char* s_q8 = (unsigned char*)s_bufA;
    {
#pragma unroll
      for (int mt = 0; mt < 2; ++mt) {
        f32x4 acc = splat4(rBQ3);
#pragma unroll
        for (int kt = 0; kt < 2; ++kt) {
          short8 a8 = *(const short8*)(s_h2 + (mt * 16 + l16) * 72 + kt * 32 + quad * 8);
          acc = mfma_bf16(a8, rWQ3[kt], acc);
        }
#pragma unroll
        for (int r = 0; r < 4; ++r)
          s_q8[(mt * 16 + quad * 4 + r) * 136 + wave * 16 + l16] = f2fp8(acc[r]);
      }
    }
    __asm__ volatile("s_waitcnt lgkmcnt(0)" ::: "memory");
    __builtin_amdgcn_sched_barrier(0);

    // ---- P4: attention — swapped-operand MFMA, P in registers, prefetched ----
    {
      const int h = wave;
      const char* sKb = (const char*)smem;
      const char* sVrow = (const char*)(smem + 65536) + (h * 16 + l16) * 512;
      long qA[2];
#pragma unroll
      for (int mt = 0; mt < 2; ++mt)
        qA[mt] = (quad < 2)
                     ? *(const long*)(s_q8 + (mt * 16 + l16) * 136 + h * 16 + quad * 8)
                     : (quad == 2 ? 0xF8L : 0L);  // byte0 = fp8 -256
      const int koff = (h * 16 + quad * 8) ^ (l16 * 8);
      f32x4 O[2], L4[2];
      O[0] = zero4; O[1] = zero4; L4[0] = zero4; L4[1] = zero4;
      // prefetch chunk 0
      long vA_c = *(const long*)(sVrow + ((quad * 8) ^ (l16 * 8)));
      long kB_c0 = 0L, kB_c1 = 0L;
      if (quad < 2) {
        kB_c0 = *(const long*)(sKb + (size_t)l16 * 128 + koff);
        kB_c1 = *(const long*)(sKb + (size_t)(16 + l16) * 128 + koff);
      }
#pragma unroll 4
      for (int c = 0; c < 16; ++c) {
        long vA_n = 0L, kB_n0 = 0L, kB_n1 = 0L;
        if (c < 15) {
          vA_n = *(const long*)(sVrow + (((c + 1) * 32 + quad * 8) ^ (l16 * 8)));
          if (quad < 2) {
            kB_n0 = *(const long*)(sKb + (size_t)((c + 1) * 32 + l16) * 128 + koff);
            kB_n1 = *(const long*)(sKb + (size_t)((c + 1) * 32 + 16 + l16) * 128 + koff);
          }
        }
        long kB0 = kB_c0, kB1 = kB_c1;
        if (quad == 2) {
          kB0 = ((mflags >> (c * 2)) & 1u) ? 0x38L : 0L;      // fp8 1.0 flag
          kB1 = ((mflags >> (c * 2 + 1)) & 1u) ? 0x38L : 0L;
        }
        f32x4 S2[2][2];
        S2[0][0] = mfma_fp8(kB0, qA[0], zero4);
        S2[0][1] = mfma_fp8(kB0, qA[1], zero4);
        S2[1][0] = mfma_fp8(kB1, qA[0], zero4);
        S2[1][1] = mfma_fp8(kB1, qA[1], zero4);
#pragma unroll
        for (int mt = 0; mt < 2; ++mt) {
          unsigned w0 = (unsigned)__builtin_amdgcn_cvt_pk_fp8_f32(
              fexp2(S2[0][mt][0]), fexp2(S2[0][mt][1]), 0, false);
          w0 = (unsigned)__builtin_amdgcn_cvt_pk_fp8_f32(
              fexp2(S2[0][mt][2]), fexp2(S2[0][mt][3]), (int)w0, true);
          unsigned w1v = (unsigned)__builtin_amdgcn_cvt_pk_fp8_f32(
              fexp2(S2[1][mt][0]), fexp2(S2[1][mt][1]), 0, false);
          w1v = (unsigned)__builtin_amdgcn_cvt_pk_fp8_f32(
              fexp2(S2[1][mt][2]), fexp2(S2[1][mt][3]), (int)w1v, true);
          long pB = (long)(((unsigned long long)w1v << 32) | (unsigned long long)w0);
          O[mt] = mfma_fp8(vA_c, pB, O[mt]);     // O^T: rows d-local, cols a
          L4[mt] = mfma_fp8(kOnes, pB, L4[mt]);
        }
        vA_c = vA_n; kB_c0 = kB_n0; kB_c1 = kB_n1;
      }
      // o -> bufB; O^T lane layout: d = h*16+quad*4+r, a = mt*16+l16
#pragma unroll
      for (int mt = 0; mt < 2; ++mt) {
        unsigned long long ow = 0;
#pragma unroll
        for (int r = 0; r < 4; ++r) {
          float o_r = O[mt][r] * frcp(L4[mt][r]);
          ow |= (unsigned long long)f2bf(o_r) << (16 * r);
        }
        *(unsigned long long*)(s_bufB + (mt * 16 + l16) * 136 + h * 16 + quad * 4) = ow;
      }
    }
    __syncthreads();

    // ---- P6: LSTM gates (x-part folded through WO; weights in regs) ----
    {
      const int ni = wave;
      f32x4 gi[2], gf[2], gg[2], go[2];
#pragma unroll
      for (int mt = 0; mt < 2; ++mt) {
        gi[mt] = splat4(rB4[0]);
        gf[mt] = splat4(rB4[1]);
        gg[mt] = splat4(rB4[2]);
        go[mt] = splat4(rB4[3]);
      }
#pragma unroll
      for (int kt = 0; kt < 4; ++kt)
#pragma unroll
        for (int mt = 0; mt < 2; ++mt) {
          short8 a8 = *(const short8*)(s_bufB + (mt * 16 + l16) * 136 + kt * 32 + quad * 8);
          gi[mt] = mfma_bf16(a8, rIH[kt][0], gi[mt]);
          gf[mt] = mfma_bf16(a8, rIH[kt][1], gf[mt]);
          gg[mt] = mfma_bf16(a8, rIH[kt][2], gg[mt]);
          go[mt] = mfma_bf16(a8, rIH[kt][3], go[mt]);
        }
#pragma unroll
      for (int kt = 0; kt < 4; ++kt)
#pragma unroll
        for (int mt = 0; mt < 2; ++mt) {
          short8 a8 = *(const short8*)(s_h + (mt * 16 + l16) * 136 + kt * 32 + quad * 8);
          gi[mt] = mfma_bf16(a8, rHH[kt][0], gi[mt]);
          gf[mt] = mfma_bf16(a8, rHH[kt][1], gf[mt]);
          gg[mt] = mfma_bf16(a8, rHH[kt][2], gg[mt]);
          go[mt] = mfma_bf16(a8, rHH[kt][3], go[mt]);
        }
      float hnew[2][4];
#pragma unroll
      for (int mt = 0; mt < 2; ++mt)
#pragma unroll
        for (int r = 0; r < 4; ++r) {
          float iv = sigm(gi[mt][r]);
          float fv = sigm(gf[mt][r]);
          float gv = tanh_f(gg[mt][r]);
          float ov = sigm(go[mt][r]);
          float cn = fmaf(fv, c_reg[mt][r], iv * gv);
          float hv = ov * tanh_f(cn);
          int arow = mt * 16 + quad * 4 + r;
          float av = avl[mt][r];
          union { unsigned int u; float f; } ho;
          ho.u = ((unsigned int)s_h[arow * 136 + ni * 16 + l16]) << 16;
          c_reg[mt][r] = av * cn + (1.f - av) * c_reg[mt][r];
          hnew[mt][r] = av * hv + (1.f - av) * ho.f;
        }
      __syncthreads();  // all h reads (incl. MFMA A-frags) done before overwrite
#pragma unroll
      for (int mt = 0; mt < 2; ++mt)
#pragma unroll
        for (int r = 0; r < 4; ++r) {
          int arow = mt * 16 + quad * 4 + r;
          s_h[arow * 136 + ni * 16 + l16] = f2bf(hnew[mt][r]);
        }
    }
    __syncthreads();

    // ---- P7+P0 fused: state += h @ lin_w^T + lin_b; emit; next h1 ----
    {
      const unsigned short* hp = s_h + p7_a * 136 + p7_sub * 16;
      const float* lw = lnw + p7_oi * 128 + p7_sub * 16;
      short8 h0 = *(const short8*)hp;
      short8 h1 = *(const short8*)(hp + 8);
      float acc = 0.f;
#pragma unroll
      for (int k = 0; k < 8; ++k) {
        union { unsigned int u; float f; } hv;
        hv.u = ((unsigned int)(unsigned short)h0[k]) << 16;
        acc = fmaf(hv.f, lw[k], acc);
      }
#pragma unroll
      for (int k = 0; k < 8; ++k) {
        union { unsigned int u; float f; } hv;
        hv.u = ((unsigned int)(unsigned short)h1[k]) << 16;
        acc = fmaf(hv.f, lw[8 + k], acc);
      }
      acc += __shfl_xor(acc, 4);
      acc += __shfl_xor(acc, 2);
      acc += __shfl_xor(acc, 1);
      float ns = myst + acc + mylnb;
      myst = ns;
      if (p7_sub == 0)
        out[((size_t)(b * 64 + a0 + p7_a) * T + t) * 2 + p7_oi] = ns;
      // P0: h1(t+1) = relu(state @ w1^T + b1) -> bufA
      float other = __shfl_xor(ns, 8);
      float st0 = p7_oi ? other : ns;
      float st1 = p7_oi ? ns : other;
      int a = tid >> 4, n0 = (tid & 15) * 8;
      const float* wp = w1 + n0 * 2;
      const float* bp = b1 + n0;
      short8 v;
#pragma unroll
      for (int j = 0; j < 8; ++j) {
        float x = fmaf(wp[j * 2], st0, fmaf(wp[j * 2 + 1], st1, bp[j]));
        v[j] = (short)f2bf(fmaxf(x, 0.f));
      }
      *(short8*)(s_bufA + a * 136 + n0) = v;
    }
    __syncthreads();
  }
}

// ---------------------------------------------------------------- launch ----
extern "C" void kernel_launch(void* const* d_in, const int* in_sizes, int n_in,
                              void* d_out, int out_size, void* d_ws, size_t ws_size,
                              hipStream_t stream) {
  (void)in_sizes; (void)n_in; (void)out_size; (void)ws_size;
  const float* cf = (const float*)d_in[0];
  const int* cav = (const int*)d_in[1];
  const float* hid = (const float*)d_in[2];
  const float* ctx = (const float*)d_in[3];
  const float* emb = (const float*)d_in[4];
  const int* mav = (const int*)d_in[5];
  const int* ntp = (const int*)d_in[6];
  const float* w1 = (const float*)d_in[7];
  const float* b1 = (const float*)d_in[8];
  const float* w2 = (const float*)d_in[9];
  const float* b2 = (const float*)d_in[10];
  const float* w3 = (const float*)d_in[11];
  const float* b3 = (const float*)d_in[12];
  const float* wq = (const float*)d_in[13];
  const float* bq = (const float*)d_in[14];
  const float* wk = (const float*)d_in[15];
  const float* bk = (const float*)d_in[16];
  const float* wv = (const float*)d_in[17];
  const float* bv = (const float*)d_in[18];
  const float* wo = (const float*)d_in[19];
  const float* bo = (const float*)d_in[20];
  const float* wih = (const float*)d_in[21];  // w_ih
  const float* whh = (const float*)d_in[22];  // w_hh
  const float* bih = (const float*)d_in[23];  // b_ih
  const float* bhh = (const float*)d_in[24];  // b_hh
  const float* lnw = (const float*)d_in[25];
  const float* lnb = (const float*)d_in[26];

  char* ws = (char*)d_ws;
  unsigned char* K8 = (unsigned char*)(ws + 0);         // 8,388,608
  unsigned char* V8 = (unsigned char*)(ws + 8388608);   // 8,388,608
  unsigned short* W2s = (unsigned short*)(ws + 16777216);   // 16,384 B
  unsigned short* WQ3s = (unsigned short*)(ws + 16793600);  // 16,384 B
  unsigned short* WIHOs = (unsigned short*)(ws + 16809984); // 131,072 B
  unsigned short* WHHs = (unsigned short*)(ws + 16941056);  // 131,072 B
  float* B4p = (float*)(ws + 17072128);                     // 2,048 B
  float* BQ3S = (float*)(ws + 17074176);                    // 512 B

  (void)hipFuncSetAttribute((const void*)prep_kernel,
                            hipFuncAttributeMaxDynamicSharedMemorySize, 99072);
  (void)hipFuncSetAttribute((const void*)decoder_kernel,
                            hipFuncAttributeMaxDynamicSharedMemorySize, 162560);

  prep_kernel<<<1603, 256, 99072, stream>>>(
      emb, wk, bk, wv, bv, w2, whh, wih, wo, wq, w3, b3, bq, bo, bih, bhh,
      K8, V8, W2s, WHHs, WIHOs, WQ3s, B4p, BQ3S);
  decoder_kernel<<<256, 512, 162560, stream>>>(
      cf, cav, hid, ctx, mav, ntp, w1, b1, b2, K8, V8, W2s, WQ3s, WIHOs, WHHs,
      B4p, BQ3S, lnw, lnb, (float*)d_out);
}

// Round 8
// 1237.975 us; speedup vs baseline: 1.7164x; 1.0140x over previous
//
#include <hip/hip_runtime.h>
#include <cstdint>
#include <cstddef>

// Decoder_55654186222328 — MI355X, R16: R15 + within-step hw bf16 pack +
// setprio around MFMA clusters.
// R15 post-mortem: recovered to 1002us decoder. LDS (162.5/163.8KB) and the
// unified VGPR/AGPR pool (128 arch + ~128 acc weights x 2 waves = full) are
// both saturated -> no occupancy or register-pipelining headroom. VALUBusy
// ~50% at 2 waves/SIMD: VALU instruction count is first-order.
// R16 (register-neutral):
//  * v_cvt_pk_bf16_f32 (asm, NON-trans VOP3 -> no R11/R12 hazard class) for
//    WITHIN-STEP packs only: h2 (P1), o (P4), h1 (P0). Recurrent s_h/h0 keep
//    software-RNE f2bf so any pk rounding delta cannot compound across steps.
//  * s_setprio(1) around P4's S-MFMA quad + PV pair and P6's MFMA burst (T5):
//    2 waves/SIMD drift within the chunk loop; MFMA-segment wave preempts the
//    exp-chain wave.
// Guard counters: VGPR must stay 128, FETCH ~23.7MB (R14 lesson).
// 256 blocks (128 b x 2 agent halves of 32) x 512 threads, 1 block/CU,
// LDS 162560 B. Barriers/step: 5.

typedef short short8 __attribute__((ext_vector_type(8)));
typedef float f32x4 __attribute__((ext_vector_type(4)));

#define LOG2E 1.4426950408889634f
#define QSCALE 0.36067376022224085f /* log2(e)/4 */

__device__ __forceinline__ unsigned short f2bf(float f) {
  union { float f; unsigned int u; } v; v.f = f;
  unsigned int u = v.u;
  return (unsigned short)((u + 0x7fffu + ((u >> 16) & 1u)) >> 16);  // RNE
}
__device__ __forceinline__ unsigned cvtpk_bf16(float lo, float hi) {
  unsigned r;
  asm("v_cvt_pk_bf16_f32 %0, %1, %2" : "=v"(r) : "v"(lo), "v"(hi));
  return r;  // [15:0]=bf16(lo) [31:16]=bf16(hi); non-trans VOP3 (no hazard)
}
__device__ __forceinline__ float fexp2(float x) {
  return __builtin_amdgcn_exp2f(x);   // v_exp_f32, compiler-managed hazards
}
__device__ __forceinline__ float frcp(float x) {
  return __builtin_amdgcn_rcpf(x);    // v_rcp_f32, compiler-managed hazards
}
__device__ __forceinline__ float sigm(float x) {
  return frcp(1.f + fexp2(-LOG2E * x));
}
__device__ __forceinline__ float tanh_f(float x) {
  return 1.f - 2.f * frcp(1.f + fexp2(2.f * LOG2E * x));
}
__device__ __forceinline__ f32x4 splat4(float v) { f32x4 r = {v, v, v, v}; return r; }
__device__ __forceinline__ unsigned char f2fp8(float x) {
  return (unsigned char)__builtin_amdgcn_cvt_pk_fp8_f32(x, x, 0, false);
}
__device__ __forceinline__ f32x4 mfma_fp8(long a, long b, f32x4 c) {
  return __builtin_amdgcn_mfma_f32_16x16x32_fp8_fp8(a, b, c, 0, 0, 0);
}
__device__ __forceinline__ f32x4 mfma_bf16(short8 a, short8 b, f32x4 c) {
  return __builtin_amdgcn_mfma_f32_16x16x32_bf16(a, b, c, 0, 0, 0);
}

// ------------------------------------------------------------ prep (merged) --
// Block roles: [0,1024) kv | [1024,1280) fold_wiho | [1280,1568) convert |
// [1568,1603) fold_wq3b. All independent -> concurrent in one launch.
// K8[b][m][128] fp8; V8[b][d][512] fp8 (transposed, m-permuted within each
// 32-token chunk: slot s holds token pi(s), pi(8q+j)=4q+j (j<4) else
// 16+4q+(j-4)).
__global__ __launch_bounds__(256) void prep_kernel(
    const float* __restrict__ emb, const float* __restrict__ wk,
    const float* __restrict__ bk, const float* __restrict__ wv,
    const float* __restrict__ bv,
    const float* __restrict__ w2, const float* __restrict__ whh,
    const float* __restrict__ wih, const float* __restrict__ wo,
    const float* __restrict__ wq, const float* __restrict__ w3,
    const float* __restrict__ b3, const float* __restrict__ bq,
    const float* __restrict__ bo, const float* __restrict__ bih,
    const float* __restrict__ bhh,
    unsigned char* __restrict__ K8, unsigned char* __restrict__ V8,
    unsigned short* __restrict__ W2, unsigned short* __restrict__ WHH,
    unsigned short* __restrict__ WIHO, unsigned short* __restrict__ WQ3,
    float* __restrict__ B4p, float* __restrict__ BQ3S) {
  extern __shared__ char smem[];
  const int tid = threadIdx.x;
  const int blk = blockIdx.x;

  if (blk < 1024) {  // ---- kv role ----
    float* s_e = (float*)smem;            // [64][129]
    float* s_w = (float*)(smem + 33024);  // [128][129]
    const int b = blk >> 3;
    const int m0 = (blk & 7) * 64;

    for (int i = tid; i < 8192; i += 256) {
      int row = i >> 7, col = i & 127;
      s_e[row * 129 + col] = emb[(size_t)(b * 512 + m0 + row) * 128 + col];
    }
    for (int i = tid; i < 16384; i += 256) {
      int row = i >> 7, col = i & 127;
      s_w[row * 129 + col] = wk[i];
    }
    __syncthreads();
    {  // K rows -> fp8
      const int dg = tid & 31, rg = tid >> 5;
      float acc[8][4];
#pragma unroll
      for (int rr = 0; rr < 8; ++rr)
#pragma unroll
        for (int j = 0; j < 4; ++j) acc[rr][j] = 0.f;
      for (int k = 0; k < 128; ++k) {
        float e[8];
#pragma unroll
        for (int rr = 0; rr < 8; ++rr) e[rr] = s_e[(rg * 8 + rr) * 129 + k];
#pragma unroll
        for (int j = 0; j < 4; ++j) {
          float w = s_w[(dg * 4 + j) * 129 + k];
#pragma unroll
          for (int rr = 0; rr < 8; ++rr) acc[rr][j] = fmaf(e[rr], w, acc[rr][j]);
        }
      }
#pragma unroll
      for (int rr = 0; rr < 8; ++rr)
#pragma unroll
        for (int j = 0; j < 4; ++j) {
          int d = dg * 4 + j;
          K8[(size_t)(b * 512 + m0 + rg * 8 + rr) * 128 + d] =
              f2fp8(acc[rr][j] + bk[d]);
        }
    }
    __syncthreads();
    for (int i = tid; i < 16384; i += 256) {
      int row = i >> 7, col = i & 127;
      s_w[row * 129 + col] = wv[i];
    }
    __syncthreads();
    {  // V transposed + m-permuted -> fp8
      const int r = tid & 63, dg = tid >> 6;
      float acc[32];
#pragma unroll
      for (int j = 0; j < 32; ++j) acc[j] = 0.f;
      for (int k = 0; k < 128; ++k) {
        float e = s_e[r * 129 + k];
#pragma unroll
        for (int j = 0; j < 32; ++j)
          acc[j] = fmaf(e, s_w[(dg * 32 + j) * 129 + k], acc[j]);
      }
      const int m = m0 + r;
      const int ml = m & 31;
      const int sperm = (ml < 16) ? (((ml >> 2) << 3) | (ml & 3))
                                  : ((((ml - 16) >> 2) << 3) | ((ml - 16) & 3) | 4);
      const int mpos = (m & ~31) | sperm;
#pragma unroll
      for (int j = 0; j < 32; ++j) {
        int d = dg * 32 + j;
        V8[(size_t)(b * 128 + d) * 512 + mpos] = f2fp8(acc[j] + bv[d]);
      }
    }
  } else if (blk < 1280) {  // ---- fold WIHO: WIHO[r][d] = wih@wo (bf16) ----
    int i = (blk - 1024) * 256 + tid;  // 65536
    int r = i >> 7, d = i & 127;
    float acc = 0.f;
    for (int n = 0; n < 128; ++n)
      acc = fmaf(wih[r * 128 + n], wo[n * 128 + d], acc);
    WIHO[i] = f2bf(acc);
  } else if (blk < 1568) {  // ---- convert W2 + WHH -> bf16 ----
    int i = (blk - 1280) * 256 + tid;
    if (i < 8192) W2[i] = f2bf(w2[i]);
    else if (i < 73728) WHH[i - 8192] = f2bf(whh[i - 8192]);
  } else {  // ---- fold WQ3 + biases ----
    int i = (blk - 1568) * 256 + tid;
    if (i < 8192) {
      int n = i >> 6, k = i & 63;
      float acc = 0.f;
      for (int j = 0; j < 128; ++j) acc = fmaf(wq[n * 128 + j], w3[j * 64 + k], acc);
      WQ3[i] = f2bf(acc * QSCALE);
    } else if (i < 8704) {
      int r = i - 8192;
      float acc = bih[r] + bhh[r];
      for (int n = 0; n < 128; ++n) acc = fmaf(wih[r * 128 + n], bo[n], acc);
      B4p[r] = acc;
    } else if (i < 8832) {
      int n = i - 8704;
      float acc = bq[n];
      for (int j = 0; j < 128; ++j) acc = fmaf(wq[n * 128 + j], b3[j], acc);
      BQ3S[n] = acc * QSCALE;
    }
  }
}

// ---------------------------------------------------------------- decoder ----
// grid 256 = 128 b x 2 agent-halves (32 agents). 512 threads = 8 waves.
// LDS (162560 B, 1 block/CU):
//   sK    @0      fp8 [512][128] XOR-swz  65536   (persistent)
//   sV    @65536  fp8 [128][512] XOR-swz  65536   (persistent, transposed+pi)
//   bufA  @131072 u16 [32][136]            8704   (h1 | qf8 bytes [32][136])
//   bufB  @139776 u16 [32][136]            8704   (o)
//   s_h   @148480 u16 [32][136]            8704
//   zone  @157184 h2 u16 [32][72]          4608
//   maskb @162048 u8 [512]                  512
// Per-step barriers (5): P1|P3+P4|P6c|P6w|P7+P0.
__global__ __launch_bounds__(512, 2) void decoder_kernel(
    const float* __restrict__ cf, const int* __restrict__ cav,
    const float* __restrict__ hid,
    const float* __restrict__ ctx, const int* __restrict__ mav,
    const int* __restrict__ ntp,
    const float* __restrict__ w1, const float* __restrict__ b1,
    const float* __restrict__ b2,
    const unsigned char* __restrict__ K8, const unsigned char* __restrict__ V8,
    const unsigned short* __restrict__ W2, const unsigned short* __restrict__ WQ3,
    const unsigned short* __restrict__ WIHO, const unsigned short* __restrict__ WHH,
    const float* __restrict__ B4p, const float* __restrict__ BQ3S,
    const float* __restrict__ lnw, const float* __restrict__ lnb,
    float* __restrict__ out) {
  extern __shared__ char smem[];
  unsigned short* s_bufA = (unsigned short*)(smem + 131072);
  unsigned short* s_bufB = (unsigned short*)(smem + 139776);
  unsigned short* s_h = (unsigned short*)(smem + 148480);
  unsigned short* s_h2 = (unsigned short*)(smem + 157184);
  unsigned char* s_maskb = (unsigned char*)(smem + 162048);

  const int tid = threadIdx.x;
  const int wave = tid >> 6;
  const int lane = tid & 63;
  const int quad = lane >> 4;
  const int l16 = lane & 15;

  const int b = blockIdx.x & 127;
  const int a0 = (blockIdx.x >> 7) * 32;
  const int T = *ntp;
  const f32x4 zero4 = {0.f, 0.f, 0.f, 0.f};
  const long kOnes = 0x3838383838383838L;  // fp8 e4m3 1.0 x8

  // ---- preload persistent K/V into LDS with XOR swizzle ----
  {
    const unsigned long long* Kg = (const unsigned long long*)(K8 + (size_t)b * 65536);
    for (int i = tid; i < 8192; i += 512) {
      int tok = i >> 4, seg = i & 15;
      *(unsigned long long*)(smem + tok * 128 + ((seg * 8) ^ ((tok & 15) * 8))) =
          Kg[(size_t)tok * 16 + seg];
    }
    const unsigned long long* Vg = (const unsigned long long*)(V8 + (size_t)b * 65536);
    for (int i = tid; i < 8192; i += 512) {
      int d = i >> 6, seg = i & 63;
      *(unsigned long long*)(smem + 65536 + d * 512 + ((seg * 8) ^ ((d & 15) * 8))) =
          Vg[(size_t)d * 64 + seg];
    }
  }
  // ---- init ----
  s_maskb[tid] = mav[b * 512 + tid] ? 1 : 0;
  {  // h0 (32 agents x 128 -> 8 per thread) — recurrent init: software RNE
    int idx = tid * 8;
    int a = idx >> 7, n0 = idx & 127;
    const float* hp = hid + (size_t)(b * 64 + a0 + a) * 128 + n0;
    short8 v;
#pragma unroll
    for (int j = 0; j < 8; ++j) v[j] = (short)f2bf(hp[j]);
    *(short8*)(s_h + a * 136 + n0) = v;
  }
  float c_reg[2][4], avl[2][4];
#pragma unroll
  for (int mt = 0; mt < 2; ++mt)
#pragma unroll
    for (int r = 0; r < 4; ++r) {
      int a = mt * 16 + quad * 4 + r;
      c_reg[mt][r] = ctx[(size_t)(b * 64 + a0 + a) * 128 + wave * 16 + l16];
      avl[mt][r] = (cav[b * 64 + a0 + a] != 0) ? 1.f : 0.f;
    }

  // ---- persistent register-cached weights (step-invariant) ----
  const int wrow = wave * 16 + l16;
  short8 rIH[4][4], rHH[4][4];
#pragma unroll
  for (int kt = 0; kt < 4; ++kt)
#pragma unroll
    for (int g = 0; g < 4; ++g) {
      rIH[kt][g] = *(const short8*)(WIHO + ((g * 128 + wrow) * 128 + kt * 32 + quad * 8));
      rHH[kt][g] = *(const short8*)(WHH + ((g * 128 + wrow) * 128 + kt * 32 + quad * 8));
    }
  short8 rWQ3[2];
#pragma unroll
  for (int kt = 0; kt < 2; ++kt)
    rWQ3[kt] = *(const short8*)(WQ3 + (wrow * 64 + kt * 32 + quad * 8));
  float rB4[4];
#pragma unroll
  for (int g = 0; g < 4; ++g) rB4[g] = B4p[g * 128 + wrow];
  const float rBQ3 = BQ3S[wrow];
  const float rB2 = b2[(wave & 3) * 16 + l16];

  // ---- fused-P7/P0 per-thread constants + register state ----
  const int p7_o = tid >> 3, p7_sub = tid & 7;
  const int p7_a = p7_o >> 1, p7_oi = p7_o & 1;
  const float mylnb = lnb[p7_oi];
  float myst = cf[(size_t)(b * 64 + a0 + p7_a) * 2 + p7_oi];

  __syncthreads();

  // per-lane mask flags: bit i set when token i*16+l16 is NOT available.
  unsigned mflags = 0;
#pragma unroll
  for (int i = 0; i < 32; ++i)
    if (!s_maskb[i * 16 + l16]) mflags |= (1u << i);

  // ---- initial h1 from initial state (P0 stand-alone; within-step pack) ----
  {
    float other = __shfl_xor(myst, 8);
    float st0 = p7_oi ? other : myst;
    float st1 = p7_oi ? myst : other;
    int a = tid >> 4, n0 = (tid & 15) * 8;
    const float* wp = w1 + n0 * 2;
    const float* bp = b1 + n0;
    float x[8];
#pragma unroll
    for (int j = 0; j < 8; ++j)
      x[j] = fmaxf(fmaf(wp[j * 2], st0, fmaf(wp[j * 2 + 1], st1, bp[j])), 0.f);
    union { short8 s; unsigned u[4]; } v;
#pragma unroll
    for (int j = 0; j < 4; ++j) v.u[j] = cvtpk_bf16(x[j * 2], x[j * 2 + 1]);
    *(short8*)(s_bufA + a * 136 + n0) = v.s;
  }
  __syncthreads();

#pragma unroll 1
  for (int t = 0; t < T; ++t) {
    // ---- P1: h2 = relu(h1 @ w2^T + b2)  M32 N64 K128 -> zone ----
    {
      int mt = wave >> 2, nt = wave & 3;
      f32x4 acc = splat4(rB2);
#pragma unroll
      for (int kt = 0; kt < 4; ++kt) {
        short8 a8 = *(const short8*)(s_bufA + (mt * 16 + l16) * 136 + kt * 32 + quad * 8);
        short8 b8 = *(const short8*)(W2 + ((nt * 16 + l16) * 128 + kt * 32 + quad * 8));
        acc = mfma_bf16(a8, b8, acc);
      }
      unsigned pk01 = cvtpk_bf16(fmaxf(acc[0], 0.f), fmaxf(acc[1], 0.f));
      unsigned pk23 = cvtpk_bf16(fmaxf(acc[2], 0.f), fmaxf(acc[3], 0.f));
      unsigned short* hb = s_h2 + (mt * 16 + quad * 4) * 72 + nt * 16 + l16;
      hb[0] = (unsigned short)pk01;
      hb[72] = (unsigned short)(pk01 >> 16);
      hb[144] = (unsigned short)pk23;
      hb[216] = (unsigned short)(pk23 >> 16);
    }
    __syncthreads();

    // ---- P3: q = h2 @ WQ3^T + bq3 -> fp8 in bufA bytes (h1 dead) ----
    // wave nt==h produces exactly head h's q-columns -> no barrier before P4.
    unsigned char* s_q8 = (unsigned char*)s_bufA;
    {
#pragma unroll
      for (int mt = 0; mt < 2; ++mt) {
        f32x4 acc = splat4(rBQ3);
#pragma unroll
        for (int kt = 0; kt < 2; ++kt) {
          short8 a8 = *(const short8*)(s_h2 + (mt * 16 + l16) * 72 + kt * 32 + quad * 8);
          acc = mfma_bf16(a8, rWQ3[kt], acc);
        }
#pragma unroll
        for (int r = 0; r < 4; ++r)
          s_q8[(mt * 16 + quad * 4 + r) * 136 + wave * 16 + l16] = f2fp8(acc[r]);
      }
    }
    __asm__ volatile("s_waitcnt lgkmcnt(0)" ::: "memory");
    __builtin_amdgcn_sched_barrier(0);

    // ---- P4: attention — swapped-operand MFMA, P in registers, prefetched ----
    {
      const int h = wave;
      const char* sKb = (const char*)smem;
      const char* sVrow = (const char*)(smem + 65536) + (h * 16 + l16) * 512;
      long qA[2];
#pragma unroll
      for (int mt = 0; mt < 2; ++mt)
        qA[mt] = (quad < 2)
                     ? *(const long*)(s_q8 + (mt * 16 + l16) * 136 + h * 16 + quad * 8)
                     : (quad == 2 ? 0xF8L : 0L);  // byte0 = fp8 -256
      const int koff = (h * 16 + quad * 8) ^ (l16 * 8);
      f32x4 O[2], L4[2];
      O[0] = zero4; O[1] = zero4; L4[0] = zero4; L4[1] = zero4;
      // prefetch chunk 0
      long vA_c = *(const long*)(sVrow + ((quad * 8) ^ (l16 * 8)));
      long kB_c0 = 0L, kB_c1 = 0L;
      if (quad < 2) {
        kB_c0 = *(const long*)(sKb + (size_t)l16 * 128 + koff);
        kB_c1 = *(const long*)(sKb + (size_t)(16 + l16) * 128 + koff);
      }
#pragma unroll 4
      for (int c = 0; c < 16; ++c) {
        long vA_n = 0L, kB_n0 = 0L, kB_n1 = 0L;
        if (c < 15) {
          vA_n = *(const long*)(sVrow + (((c + 1) * 32 + quad * 8) ^ (l16 * 8)));
          if (quad < 2) {
            kB_n0 = *(const long*)(sKb + (size_t)((c + 1) * 32 + l16) * 128 + koff);
            kB_n1 = *(const long*)(sKb + (size_t)((c + 1) * 32 + 16 + l16) * 128 + koff);
          }
        }
        long kB0 = kB_c0, kB1 = kB_c1;
        if (quad == 2) {
          kB0 = ((mflags >> (c * 2)) & 1u) ? 0x38L : 0L;      // fp8 1.0 flag
          kB1 = ((mflags >> (c * 2 + 1)) & 1u) ? 0x38L : 0L;
        }
        __builtin_amdgcn_s_setprio(1);
        f32x4 S2[2][2];
        S2[0][0] = mfma_fp8(kB0, qA[0], zero4);
        S2[0][1] = mfma_fp8(kB0, qA[1], zero4);
        S2[1][0] = mfma_fp8(kB1, qA[0], zero4);
        S2[1][1] = mfma_fp8(kB1, qA[1], zero4);
        __builtin_amdgcn_s_setprio(0);
        long pB[2];
#pragma unroll
        for (int mt = 0; mt < 2; ++mt) {
          unsigned w0 = (unsigned)__builtin_amdgcn_cvt_pk_fp8_f32(
              fexp2(S2[0][mt][0]), fexp2(S2[0][mt][1]), 0, false);
          w0 = (unsigned)__builtin_amdgcn_cvt_pk_fp8_f32(
              fexp2(S2[0][mt][2]), fexp2(S2[0][mt][3]), (int)w0, true);
          unsigned w1v = (unsigned)__builtin_amdgcn_cvt_pk_fp8_f32(
              fexp2(S2[1][mt][0]), fexp2(S2[1][mt][1]), 0, false);
          w1v = (unsigned)__builtin_amdgcn_cvt_pk_fp8_f32(
              fexp2(S2[1][mt][2]), fexp2(S2[1][mt][3]), (int)w1v, true);
          pB[mt] = (long)(((unsigned long long)w1v << 32) | (unsigned long long)w0);
        }
        __builtin_amdgcn_s_setprio(1);
        O[0] = mfma_fp8(vA_c, pB[0], O[0]);     // O^T: rows d-local, cols a
        L4[0] = mfma_fp8(kOnes, pB[0], L4[0]);
        O[1] = mfma_fp8(vA_c, pB[1], O[1]);
        L4[1] = mfma_fp8(kOnes, pB[1], L4[1]);
        __builtin_amdgcn_s_setprio(0);
        vA_c = vA_n; kB_c0 = kB_n0; kB_c1 = kB_n1;
      }
      // o -> bufB (within-step pack); O^T: d = h*16+quad*4+r, a = mt*16+l16
#pragma unroll
      for (int mt = 0; mt < 2; ++mt) {
        float o0 = O[mt][0] * frcp(L4[mt][0]);
        float o1 = O[mt][1] * frcp(L4[mt][1]);
        float o2 = O[mt][2] * frcp(L4[mt][2]);
        float o3 = O[mt][3] * frcp(L4[mt][3]);
        unsigned long long ow =
            ((unsigned long long)cvtpk_bf16(o2, o3) << 32) | cvtpk_bf16(o0, o1);
        *(unsigned long long*)(s_bufB + (mt * 16 + l16) * 136 + h * 16 + quad * 4) = ow;
      }
    }
    __syncthreads();

    // ---- P6: LSTM gates (x-part folded through WO; weights in regs) ----
    {
      const int ni = wave;
      f32x4 gi[2], gf[2], gg[2], go[2];
#pragma unroll
      for (int mt = 0; mt < 2; ++mt) {
        gi[mt] = splat4(rB4[0]);
        gf[mt] = splat4(rB4[1]);
        gg[mt] = splat4(rB4[2]);
        go[mt] = splat4(rB4[3]);
      }
      __builtin_amdgcn_s_setprio(1);
#pragma unroll
      for (int kt = 0; kt < 4; ++kt)
#pragma unroll
        for (int mt = 0; mt < 2; ++mt) {
          short8 a8 = *(const short8*)(s_bufB + (mt * 16 + l16) * 136 + kt * 32 + quad * 8);
          gi[mt] = mfma_bf16(a8, rIH[kt][0], gi[mt]);
          gf[mt] = mfma_bf16(a8, rIH[kt][1], gf[mt]);
          gg[mt] = mfma_bf16(a8, rIH[kt][2], gg[mt]);
          go[mt] = mfma_bf16(a8, rIH[kt][3], go[mt]);
        }
#pragma unroll
      for (int kt = 0; kt < 4; ++kt)
#pragma unroll
        for (int mt = 0; mt < 2; ++mt) {
          short8 a8 = *(const short8*)(s_h + (mt * 16 + l16) * 136 + kt * 32 + quad * 8);
          gi[mt] = mfma_bf16(a8, rHH[kt][0], gi[mt]);
          gf[mt] = mfma_bf16(a8, rHH[kt][1], gf[mt]);
          gg[mt] = mfma_bf16(a8, rHH[kt][2], gg[mt]);
          go[mt] = mfma_bf16(a8, rHH[kt][3], go[mt]);
        }
      __builtin_amdgcn_s_setprio(0);
      float hnew[2][4];
#pragma unroll
      for (int mt = 0; mt < 2; ++mt)
#pragma unroll
        for (int r = 0; r < 4; ++r) {
          float iv = sigm(gi[mt][r]);
          float fv = sigm(gf[mt][r]);
          float gv = tanh_f(gg[mt][r]);
          float ov = sigm(go[mt][r]);
          float cn = fmaf(fv, c_reg[mt][r], iv * gv);
          float hv = ov * tanh_f(cn);
          int arow = mt * 16 + quad * 4 + r;
          float av = avl[mt][r];
          union { unsigned int u; float f; } ho;
          ho.u = ((unsigned int)s_h[arow * 136 + ni * 16 + l16]) << 16;
          c_reg[mt][r] = av * cn + (1.f - av) * c_reg[mt][r];
          hnew[mt][r] = av * hv + (1.f - av) * ho.f;
        }
      __syncthreads();  // all h reads (incl. MFMA A-frags) done before overwrite
#pragma unroll
      for (int mt = 0; mt < 2; ++mt)
#pragma unroll
        for (int r = 0; r < 4; ++r) {
          int arow = mt * 16 + quad * 4 + r;
          s_h[arow * 136 + ni * 16 + l16] = f2bf(hnew[mt][r]);  // recurrent: RNE
        }
    }
    __syncthreads();

    // ---- P7+P0 fused: state += h @ lin_w^T + lin_b; emit; next h1 ----
    {
      const unsigned short* hp = s_h + p7_a * 136 + p7_sub * 16;
      const float* lw = lnw + p7_oi * 128 + p7_sub * 16;
      short8 h0 = *(const short8*)hp;
      short8 h1 = *(const short8*)(hp + 8);
      float acc = 0.f;
#pragma unroll
      for (int k = 0; k < 8; ++k) {
        union { unsigned int u; float f; } hv;
        hv.u = ((unsigned int)(unsigned short)h0[k]) << 16;
        acc = fmaf(hv.f, lw[k], acc);
      }
#pragma unroll
      for (int k = 0; k < 8; ++k) {
        union { unsigned int u; float f; } hv;
        hv.u = ((unsigned int)(unsigned short)h1[k]) << 16;
        acc = fmaf(hv.f, lw[8 + k], acc);
      }
      acc += __shfl_xor(acc, 4);
      acc += __shfl_xor(acc, 2);
      acc += __shfl_xor(acc, 1);
      float ns = myst + acc + mylnb;
      myst = ns;
      if (p7_sub == 0)
        out[((size_t)(b * 64 + a0 + p7_a) * T + t) * 2 + p7_oi] = ns;
      // P0: h1(t+1) = relu(state @ w1^T + b1) -> bufA (within-step pack)
      float other = __shfl_xor(ns, 8);
      float st0 = p7_oi ? other : ns;
      float st1 = p7_oi ? ns : other;
      int a = tid >> 4, n0 = (tid & 15) * 8;
      const float* wp = w1 + n0 * 2;
      const float* bp = b1 + n0;
      float x[8];
#pragma unroll
      for (int j = 0; j < 8; ++j)
        x[j] = fmaxf(fmaf(wp[j * 2], st0, fmaf(wp[j * 2 + 1], st1, bp[j])), 0.f);
      union { short8 s; unsigned u[4]; } v;
#pragma unroll
      for (int j = 0; j < 4; ++j) v.u[j] = cvtpk_bf16(x[j * 2], x[j * 2 + 1]);
      *(short8*)(s_bufA + a * 136 + n0) = v.s;
    }
    __syncthreads();
  }
}

// ---------------------------------------------------------------- launch ----
extern "C" void kernel_launch(void* const* d_in, const int* in_sizes, int n_in,
                              void* d_out, int out_size, void* d_ws, size_t ws_size,
                              hipStream_t stream) {
  (void)in_sizes; (void)n_in; (void)out_size; (void)ws_size;
  const float* cf = (const float*)d_in[0];
  const int* cav = (const int*)d_in[1];
  const float* hid = (const float*)d_in[2];
  const float* ctx = (const float*)d_in[3];
  const float* emb = (const float*)d_in[4];
  const int* mav = (const int*)d_in[5];
  const int* ntp = (const int*)d_in[6];
  const float* w1 = (const float*)d_in[7];
  const float* b1 = (const float*)d_in[8];
  const float* w2 = (const float*)d_in[9];
  const float* b2 = (const float*)d_in[10];
  const float* w3 = (const float*)d_in[11];
  const float* b3 = (const float*)d_in[12];
  const float* wq = (const float*)d_in[13];
  const float* bq = (const float*)d_in[14];
  const float* wk = (const float*)d_in[15];
  const float* bk = (const float*)d_in[16];
  const float* wv = (const float*)d_in[17];
  const float* bv = (const float*)d_in[18];
  const float* wo = (const float*)d_in[19];
  const float* bo = (const float*)d_in[20];
  const float* wih = (const float*)d_in[21];  // w_ih
  const float* whh = (const float*)d_in[22];  // w_hh
  const float* bih = (const float*)d_in[23];  // b_ih
  const float* bhh = (const float*)d_in[24];  // b_hh
  const float* lnw = (const float*)d_in[25];
  const float* lnb = (const float*)d_in[26];

  char* ws = (char*)d_ws;
  unsigned char* K8 = (unsigned char*)(ws + 0);         // 8,388,608
  unsigned char* V8 = (unsigned char*)(ws + 8388608);   // 8,388,608
  unsigned short* W2s = (unsigned short*)(ws + 16777216);   // 16,384 B
  unsigned short* WQ3s = (unsigned short*)(ws + 16793600);  // 16,384 B
  unsigned short* WIHOs = (unsigned short*)(ws + 16809984); // 131,072 B
  unsigned short* WHHs = (unsigned short*)(ws + 16941056);  // 131,072 B
  float* B4p = (float*)(ws + 17072128);                     // 2,048 B
  float* BQ3S = (float*)(ws + 17074176);                    // 512 B

  (void)hipFuncSetAttribute((const void*)prep_kernel,
                            hipFuncAttributeMaxDynamicSharedMemorySize, 99072);
  (void)hipFuncSetAttribute((const void*)decoder_kernel,
                            hipFuncAttributeMaxDynamicSharedMemorySize, 162560);

  prep_kernel<<<1603, 256, 99072, stream>>>(
      emb, wk, bk, wv, bv, w2, whh, wih, wo, wq, w3, b3, bq, bo, bih, bhh,
      K8, V8, W2s, WHHs, WIHOs, WQ3s, B4p, BQ3S);
  decoder_kernel<<<256, 512, 162560, stream>>>(
      cf, cav, hid, ctx, mav, ntp, w1, b1, b2, K8, V8, W2s, WQ3s, WIHOs, WHHs,
      B4p, BQ3S, lnw, lnb, (float*)d_out);
}

// Round 9
// 1117.171 us; speedup vs baseline: 1.9020x; 1.1081x over previous
//
#include <hip/hip_runtime.h>
#include <cstdint>
#include <cstddef>

// Decoder_55654186222328 — MI355X, R17: prep kv-role rewritten as bf16 MFMA
// GEMM. Decoder byte-identical to R16 (989us, passed).
// R16 post-mortem: decoder gains exhausted for now (register file exactly
// full: 128 VGPR + 128 AGPR weights x 2 waves = 512-reg pool; LDS full).
// But prep = ~250us of the 1238us wall (20%!): its kv-role does 4.3 GFLOP of
// K/V projection with scalar f32 FMAs + stride-129 LDS reads (~100x off
// roofline; V-phase alone ~24K cyc/wave of ds_read_b32).
// R17: kv-role = staged bf16 MFMA GEMM (e,wk,wv -> LDS bf16 [r][136], pad-8
// proven in decoder P1). K: C[m][d]=e@wk^T (P1's exact fragment pattern).
// V: C[d][m]=wv@e^T -> output born transposed; pi-permutation + fp8 at write.
// Numerics: bf16 (2^-8) rounding before an fp8-quantized (2^-4) output,
// non-recurrent -> negligible. Other prep roles + decoder untouched.
// Prep LDS: 87040 B. Decoder unchanged: 256x512, 1 block/CU, 162560 B.

typedef short short8 __attribute__((ext_vector_type(8)));
typedef float f32x4 __attribute__((ext_vector_type(4)));

#define LOG2E 1.4426950408889634f
#define QSCALE 0.36067376022224085f /* log2(e)/4 */

__device__ __forceinline__ unsigned short f2bf(float f) {
  union { float f; unsigned int u; } v; v.f = f;
  unsigned int u = v.u;
  return (unsigned short)((u + 0x7fffu + ((u >> 16) & 1u)) >> 16);  // RNE
}
__device__ __forceinline__ unsigned cvtpk_bf16(float lo, float hi) {
  unsigned r;
  asm("v_cvt_pk_bf16_f32 %0, %1, %2" : "=v"(r) : "v"(lo), "v"(hi));
  return r;  // [15:0]=bf16(lo) [31:16]=bf16(hi); non-trans VOP3 (no hazard)
}
__device__ __forceinline__ float fexp2(float x) {
  return __builtin_amdgcn_exp2f(x);   // v_exp_f32, compiler-managed hazards
}
__device__ __forceinline__ float frcp(float x) {
  return __builtin_amdgcn_rcpf(x);    // v_rcp_f32, compiler-managed hazards
}
__device__ __forceinline__ float sigm(float x) {
  return frcp(1.f + fexp2(-LOG2E * x));
}
__device__ __forceinline__ float tanh_f(float x) {
  return 1.f - 2.f * frcp(1.f + fexp2(2.f * LOG2E * x));
}
__device__ __forceinline__ f32x4 splat4(float v) { f32x4 r = {v, v, v, v}; return r; }
__device__ __forceinline__ unsigned char f2fp8(float x) {
  return (unsigned char)__builtin_amdgcn_cvt_pk_fp8_f32(x, x, 0, false);
}
__device__ __forceinline__ f32x4 mfma_fp8(long a, long b, f32x4 c) {
  return __builtin_amdgcn_mfma_f32_16x16x32_fp8_fp8(a, b, c, 0, 0, 0);
}
__device__ __forceinline__ f32x4 mfma_bf16(short8 a, short8 b, f32x4 c) {
  return __builtin_amdgcn_mfma_f32_16x16x32_bf16(a, b, c, 0, 0, 0);
}

// ------------------------------------------------------------ prep (merged) --
// Block roles: [0,1024) kv-GEMM | [1024,1280) fold_wiho | [1280,1568) convert |
// [1568,1603) fold_wq3b. All independent -> concurrent in one launch.
// K8[b][m][128] fp8; V8[b][d][512] fp8 (transposed, m-permuted within each
// 32-token chunk: slot s holds token pi(s), pi(8q+j)=4q+j (j<4) else
// 16+4q+(j-4)).
// kv-role LDS: s_e bf16[64][136] @0 (17408) | s_wk bf16[128][136] @17408
// (34816) | s_wv bf16[128][136] @52224 (34816). Total 87040 B.
__global__ __launch_bounds__(256) void prep_kernel(
    const float* __restrict__ emb, const float* __restrict__ wk,
    const float* __restrict__ bk, const float* __restrict__ wv,
    const float* __restrict__ bv,
    const float* __restrict__ w2, const float* __restrict__ whh,
    const float* __restrict__ wih, const float* __restrict__ wo,
    const float* __restrict__ wq, const float* __restrict__ w3,
    const float* __restrict__ b3, const float* __restrict__ bq,
    const float* __restrict__ bo, const float* __restrict__ bih,
    const float* __restrict__ bhh,
    unsigned char* __restrict__ K8, unsigned char* __restrict__ V8,
    unsigned short* __restrict__ W2, unsigned short* __restrict__ WHH,
    unsigned short* __restrict__ WIHO, unsigned short* __restrict__ WQ3,
    float* __restrict__ B4p, float* __restrict__ BQ3S) {
  extern __shared__ char smem[];
  const int tid = threadIdx.x;
  const int blk = blockIdx.x;

  if (blk < 1024) {  // ---- kv role: bf16 MFMA GEMM ----
    unsigned short* s_e = (unsigned short*)smem;             // [64][136]
    unsigned short* s_wk = (unsigned short*)(smem + 17408);  // [128][136]
    unsigned short* s_wv = (unsigned short*)(smem + 52224);  // [128][136]
    const int b = blk >> 3;
    const int m0 = (blk & 7) * 64;
    const int wave = tid >> 6;
    const int lane = tid & 63;
    const int quad = lane >> 4;
    const int l16 = lane & 15;

    // stage (pairs -> u32 writes; col even so 4B-aligned)
    for (int i = tid; i < 4096; i += 256) {
      int j = i * 2, row = j >> 7, col = j & 127;
      const float* p = emb + (size_t)(b * 512 + m0 + row) * 128 + col;
      *(unsigned*)(s_e + row * 136 + col) = cvtpk_bf16(p[0], p[1]);
    }
    for (int i = tid; i < 8192; i += 256) {
      int j = i * 2, row = j >> 7, col = j & 127;
      *(unsigned*)(s_wk + row * 136 + col) =
          cvtpk_bf16(wk[row * 128 + col], wk[row * 128 + col + 1]);
      *(unsigned*)(s_wv + row * 136 + col) =
          cvtpk_bf16(wv[row * 128 + col], wv[row * 128 + col + 1]);
    }
    __syncthreads();

    {  // K-phase: C[m][d] = e @ wk^T  (M64 N128 K128; wave = m-tile)
      const int mt = wave;
      short8 a8[4];
#pragma unroll
      for (int kt = 0; kt < 4; ++kt)
        a8[kt] = *(const short8*)(s_e + (mt * 16 + l16) * 136 + kt * 32 + quad * 8);
#pragma unroll
      for (int nt = 0; nt < 8; ++nt) {
        f32x4 acc = {0.f, 0.f, 0.f, 0.f};
#pragma unroll
        for (int kt = 0; kt < 4; ++kt) {
          short8 b8 = *(const short8*)(s_wk + (nt * 16 + l16) * 136 + kt * 32 + quad * 8);
          acc = mfma_bf16(a8[kt], b8, acc);
        }
        const int d = nt * 16 + l16;
        const float bkd = bk[d];
#pragma unroll
        for (int r = 0; r < 4; ++r)
          K8[(size_t)(b * 512 + m0 + mt * 16 + quad * 4 + r) * 128 + d] =
              f2fp8(acc[r] + bkd);
      }
    }
    {  // V-phase: C[d][m] = wv @ e^T (M128 N64 K128; born transposed)
      const int dt0 = wave * 2;
#pragma unroll
      for (int dt = dt0; dt < dt0 + 2; ++dt) {
        short8 a8[4];
#pragma unroll
        for (int kt = 0; kt < 4; ++kt)
          a8[kt] = *(const short8*)(s_wv + (dt * 16 + l16) * 136 + kt * 32 + quad * 8);
#pragma unroll
        for (int nt = 0; nt < 4; ++nt) {
          f32x4 acc = {0.f, 0.f, 0.f, 0.f};
#pragma unroll
          for (int kt = 0; kt < 4; ++kt) {
            short8 b8 = *(const short8*)(s_e + (nt * 16 + l16) * 136 + kt * 32 + quad * 8);
            acc = mfma_bf16(a8[kt], b8, acc);
          }
          const int m = m0 + nt * 16 + l16;
          const int ml = m & 31;
          const int sperm = (ml < 16) ? (((ml >> 2) << 3) | (ml & 3))
                                      : ((((ml - 16) >> 2) << 3) | ((ml - 16) & 3) | 4);
          const int mpos = (m & ~31) | sperm;
#pragma unroll
          for (int r = 0; r < 4; ++r) {
            const int d = dt * 16 + quad * 4 + r;
            V8[(size_t)(b * 128 + d) * 512 + mpos] = f2fp8(acc[r] + bv[d]);
          }
        }
      }
    }
  } else if (blk < 1280) {  // ---- fold WIHO: WIHO[r][d] = wih@wo (bf16) ----
    int i = (blk - 1024) * 256 + tid;  // 65536
    int r = i >> 7, d = i & 127;
    float acc = 0.f;
    for (int n = 0; n < 128; ++n)
      acc = fmaf(wih[r * 128 + n], wo[n * 128 + d], acc);
    WIHO[i] = f2bf(acc);
  } else if (blk < 1568) {  // ---- convert W2 + WHH -> bf16 ----
    int i = (blk - 1280) * 256 + tid;
    if (i < 8192) W2[i] = f2bf(w2[i]);
    else if (i < 73728) WHH[i - 8192] = f2bf(whh[i - 8192]);
  } else {  // ---- fold WQ3 + biases ----
    int i = (blk - 1568) * 256 + tid;
    if (i < 8192) {
      int n = i >> 6, k = i & 63;
      float acc = 0.f;
      for (int j = 0; j < 128; ++j) acc = fmaf(wq[n * 128 + j], w3[j * 64 + k], acc);
      WQ3[i] = f2bf(acc * QSCALE);
    } else if (i < 8704) {
      int r = i - 8192;
      float acc = bih[r] + bhh[r];
      for (int n = 0; n < 128; ++n) acc = fmaf(wih[r * 128 + n], bo[n], acc);
      B4p[r] = acc;
    } else if (i < 8832) {
      int n = i - 8704;
      float acc = bq[n];
      for (int j = 0; j < 128; ++j) acc = fmaf(wq[n * 128 + j], b3[j], acc);
      BQ3S[n] = acc * QSCALE;
    }
  }
}

// ---------------------------------------------------------------- decoder ----
// grid 256 = 128 b x 2 agent-halves (32 agents). 512 threads = 8 waves.
// LDS (162560 B, 1 block/CU):
//   sK    @0      fp8 [512][128] XOR-swz  65536   (persistent)
//   sV    @65536  fp8 [128][512] XOR-swz  65536   (persistent, transposed+pi)
//   bufA  @131072 u16 [32][136]            8704   (h1 | qf8 bytes [32][136])
//   bufB  @139776 u16 [32][136]            8704   (o)
//   s_h   @148480 u16 [32][136]            8704
//   zone  @157184 h2 u16 [32][72]          4608
//   maskb @162048 u8 [512]                  512
// Per-step barriers (5): P1|P3+P4|P6c|P6w|P7+P0.  (R16 verbatim.)
__global__ __launch_bounds__(512, 2) void decoder_kernel(
    const float* __restrict__ cf, const int* __restrict__ cav,
    const float* __restrict__ hid,
    const float* __restrict__ ctx, const int* __restrict__ mav,
    const int* __restrict__ ntp,
    const float* __restrict__ w1, const float* __restrict__ b1,
    const float* __restrict__ b2,
    const unsigned char* __restrict__ K8, const unsigned char* __restrict__ V8,
    const unsigned short* __restrict__ W2, const unsigned short* __restrict__ WQ3,
    const unsigned short* __restrict__ WIHO, const unsigned short* __restrict__ WHH,
    const float* __restrict__ B4p, const float* __restrict__ BQ3S,
    const float* __restrict__ lnw, const float* __restrict__ lnb,
    float* __restrict__ out) {
  extern __shared__ char smem[];
  unsigned short* s_bufA = (unsigned short*)(smem + 131072);
  unsigned short* s_bufB = (unsigned short*)(smem + 139776);
  unsigned short* s_h = (unsigned short*)(smem + 148480);
  unsigned short* s_h2 = (unsigned short*)(smem + 157184);
  unsigned char* s_maskb = (unsigned char*)(smem + 162048);

  const int tid = threadIdx.x;
  const int wave = tid >> 6;
  const int lane = tid & 63;
  const int quad = lane >> 4;
  const int l16 = lane & 15;

  const int b = blockIdx.x & 127;
  const int a0 = (blockIdx.x >> 7) * 32;
  const int T = *ntp;
  const f32x4 zero4 = {0.f, 0.f, 0.f, 0.f};
  const long kOnes = 0x3838383838383838L;  // fp8 e4m3 1.0 x8

  // ---- preload persistent K/V into LDS with XOR swizzle ----
  {
    const unsigned long long* Kg = (const unsigned long long*)(K8 + (size_t)b * 65536);
    for (int i = tid; i < 8192; i += 512) {
      int tok = i >> 4, seg = i & 15;
      *(unsigned long long*)(smem + tok * 128 + ((seg * 8) ^ ((tok & 15) * 8))) =
          Kg[(size_t)tok * 16 + seg];
    }
    const unsigned long long* Vg = (const unsigned long long*)(V8 + (size_t)b * 65536);
    for (int i = tid; i < 8192; i += 512) {
      int d = i >> 6, seg = i & 63;
      *(unsigned long long*)(smem + 65536 + d * 512 + ((seg * 8) ^ ((d & 15) * 8))) =
          Vg[(size_t)d * 64 + seg];
    }
  }
  // ---- init ----
  s_maskb[tid] = mav[b * 512 + tid] ? 1 : 0;
  {  // h0 (32 agents x 128 -> 8 per thread) — recurrent init: software RNE
    int idx = tid * 8;
    int a = idx >> 7, n0 = idx & 127;
    const float* hp = hid + (size_t)(b * 64 + a0 + a) * 128 + n0;
    short8 v;
#pragma unroll
    for (int j = 0; j < 8; ++j) v[j] = (short)f2bf(hp[j]);
    *(short8*)(s_h + a * 136 + n0) = v;
  }
  float c_reg[2][4], avl[2][4];
#pragma unroll
  for (int mt = 0; mt < 2; ++mt)
#pragma unroll
    for (int r = 0; r < 4; ++r) {
      int a = mt * 16 + quad * 4 + r;
      c_reg[mt][r] = ctx[(size_t)(b * 64 + a0 + a) * 128 + wave * 16 + l16];
      avl[mt][r] = (cav[b * 64 + a0 + a] != 0) ? 1.f : 0.f;
    }

  // ---- persistent register-cached weights (step-invariant) ----
  const int wrow = wave * 16 + l16;
  short8 rIH[4][4], rHH[4][4];
#pragma unroll
  for (int kt = 0; kt < 4; ++kt)
#pragma unroll
    for (int g = 0; g < 4; ++g) {
      rIH[kt][g] = *(const short8*)(WIHO + ((g * 128 + wrow) * 128 + kt * 32 + quad * 8));
      rHH[kt][g] = *(const short8*)(WHH + ((g * 128 + wrow) * 128 + kt * 32 + quad * 8));
    }
  short8 rWQ3[2];
#pragma unroll
  for (int kt = 0; kt < 2; ++kt)
    rWQ3[kt] = *(const short8*)(WQ3 + (wrow * 64 + kt * 32 + quad * 8));
  float rB4[4];
#pragma unroll
  for (int g = 0; g < 4; ++g) rB4[g] = B4p[g * 128 + wrow];
  const float rBQ3 = BQ3S[wrow];
  const float rB2 = b2[(wave & 3) * 16 + l16];

  // ---- fused-P7/P0 per-thread constants + register state ----
  const int p7_o = tid >> 3, p7_sub = tid & 7;
  const int p7_a = p7_o >> 1, p7_oi = p7_o & 1;
  const float mylnb = lnb[p7_oi];
  float myst = cf[(size_t)(b * 64 + a0 + p7_a) * 2 + p7_oi];

  __syncthreads();

  // per-lane mask flags: bit i set when token i*16+l16 is NOT available.
  unsigned mflags = 0;
#pragma unroll
  for (int i = 0; i < 32; ++i)
    if (!s_maskb[i * 16 + l16]) mflags |= (1u << i);

  // ---- initial h1 from initial state (P0 stand-alone; within-step pack) ----
  {
    float other = __shfl_xor(myst, 8);
    float st0 = p7_oi ? other : myst;
    float st1 = p7_oi ? myst : other;
    int a = tid >> 4, n0 = (tid & 15) * 8;
    const float* wp = w1 + n0 * 2;
    const float* bp = b1 + n0;
    float x[8];
#pragma unroll
    for (int j = 0; j < 8; ++j)
      x[j] = fmaxf(fmaf(wp[j * 2], st0, fmaf(wp[j * 2 + 1], st1, bp[j])), 0.f);
    union { short8 s; unsigned u[4]; } v;
#pragma unroll
    for (int j = 0; j < 4; ++j) v.u[j] = cvtpk_bf16(x[j * 2], x[j * 2 + 1]);
    *(short8*)(s_bufA + a * 136 + n0) = v.s;
  }
  __syncthreads();

#pragma unroll 1
  for (int t = 0; t < T; ++t) {
    // ---- P1: h2 = relu(h1 @ w2^T + b2)  M32 N64 K128 -> zone ----
    {
      int mt = wave >> 2, nt = wave & 3;
      f32x4 acc = splat4(rB2);
#pragma unroll
      for (int kt = 0; kt < 4; ++kt) {
        short8 a8 = *(const short8*)(s_bufA + (mt * 16 + l16) * 136 + kt * 32 + quad * 8);
        short8 b8 = *(const short8*)(W2 + ((nt * 16 + l16) * 128 + kt * 32 + quad * 8));
        acc = mfma_bf16(a8, b8, acc);
      }
      unsigned pk01 = cvtpk_bf16(fmaxf(acc[0], 0.f), fmaxf(acc[1], 0.f));
      unsigned pk23 = cvtpk_bf16(fmaxf(acc[2], 0.f), fmaxf(acc[3], 0.f));
      unsigned short* hb = s_h2 + (mt * 16 + quad * 4) * 72 + nt * 16 + l16;
      hb[0] = (unsigned short)pk01;
      hb[72] = (unsigned short)(pk01 >> 16);
      hb[144] = (unsigned short)pk23;
      hb[216] = (unsigned short)(pk23 >> 16);
    }
    __syncthreads();

    // ---- P3: q = h2 @ WQ3^T + bq3 -> fp8 in bufA bytes (h1 dead) ----
    // wave nt==h produces exactly head h's q-columns -> no barrier before P4.
    unsigned char* s_q8 = (unsigned char*)s_bufA;
    {
#pragma unroll
      for (int mt = 0; mt < 2; ++mt) {
        f32x4 acc = splat4(rBQ3);
#pragma unroll
        for (int kt = 0; kt < 2; ++kt) {
          short8 a8 = *(const short8*)(s_h2 + (mt * 16 + l16) * 72 + kt * 32 + quad * 8);
          acc = mfma_bf16(a8, rWQ3[kt], acc);
        }
#pragma unroll
        for (int r = 0; r < 4; ++r)
          s_q8[(mt * 16 + quad * 4 + r) * 136 + wave * 16 + l16] = f2fp8(acc[r]);
      }
    }
    __asm__ volatile("s_waitcnt lgkmcnt(0)" ::: "memory");
    __builtin_amdgcn_sched_barrier(0);

    // ---- P4: attention — swapped-operand MFMA, P in registers, prefetched ----
    {
      const int h = wave;
      const char* sKb = (const char*)smem;
      const char* sVrow = (const char*)(smem + 65536) + (h * 16 + l16) * 512;
      long qA[2];
#pragma unroll
      for (int mt = 0; mt < 2; ++mt)
        qA[mt] = (quad < 2)
                     ? *(const long*)(s_q8 + (mt * 16 + l16) * 136 + h * 16 + quad * 8)
                     : (quad == 2 ? 0xF8L : 0L);  // byte0 = fp8 -256
      const int koff = (h * 16 + quad * 8) ^ (l16 * 8);
      f32x4 O[2], L4[2];
      O[0] = zero4; O[1] = zero4; L4[0] = zero4; L4[1] = zero4;
      // prefetch chunk 0
      long vA_c = *(const long*)(sVrow + ((quad * 8) ^ (l16 * 8)));
      long kB_c0 = 0L, kB_c1 = 0L;
      if (quad < 2) {
        kB_c0 = *(const long*)(sKb + (size_t)l16 * 128 + koff);
        kB_c1 = *(const long*)(sKb + (size_t)(16 + l16) * 128 + koff);
      }
#pragma unroll 4
      for (int c = 0; c < 16; ++c) {
        long vA_n = 0L, kB_n0 = 0L, kB_n1 = 0L;
        if (c < 15) {
          vA_n = *(const long*)(sVrow + (((c + 1) * 32 + quad * 8) ^ (l16 * 8)));
          if (quad < 2) {
            kB_n0 = *(const long*)(sKb + (size_t)((c + 1) * 32 + l16) * 128 + koff);
            kB_n1 = *(const long*)(sKb + (size_t)((c + 1) * 32 + 16 + l16) * 128 + koff);
          }
        }
        long kB0 = kB_c0, kB1 = kB_c1;
        if (quad == 2) {
          kB0 = ((mflags >> (c * 2)) & 1u) ? 0x38L : 0L;      // fp8 1.0 flag
          kB1 = ((mflags >> (c * 2 + 1)) & 1u) ? 0x38L : 0L;
        }
        __builtin_amdgcn_s_setprio(1);
        f32x4 S2[2][2];
        S2[0][0] = mfma_fp8(kB0, qA[0], zero4);
        S2[0][1] = mfma_fp8(kB0, qA[1], zero4);
        S2[1][0] = mfma_fp8(kB1, qA[0], zero4);
        S2[1][1] = mfma_fp8(kB1, qA[1], zero4);
        __builtin_amdgcn_s_setprio(0);
        long pB[2];
#pragma unroll
        for (int mt = 0; mt < 2; ++mt) {
          unsigned w0 = (unsigned)__builtin_amdgcn_cvt_pk_fp8_f32(
              fexp2(S2[0][mt][0]), fexp2(S2[0][mt][1]), 0, false);
          w0 = (unsigned)__builtin_amdgcn_cvt_pk_fp8_f32(
              fexp2(S2[0][mt][2]), fexp2(S2[0][mt][3]), (int)w0, true);
          unsigned w1v = (unsigned)__builtin_amdgcn_cvt_pk_fp8_f32(
              fexp2(S2[1][mt][0]), fexp2(S2[1][mt][1]), 0, false);
          w1v = (unsigned)__builtin_amdgcn_cvt_pk_fp8_f32(
              fexp2(S2[1][mt][2]), fexp2(S2[1][mt][3]), (int)w1v, true);
          pB[mt] = (long)(((unsigned long long)w1v << 32) | (unsigned long long)w0);
        }
        __builtin_amdgcn_s_setprio(1);
        O[0] = mfma_fp8(vA_c, pB[0], O[0]);     // O^T: rows d-local, cols a
        L4[0] = mfma_fp8(kOnes, pB[0], L4[0]);
        O[1] = mfma_fp8(vA_c, pB[1], O[1]);
        L4[1] = mfma_fp8(kOnes, pB[1], L4[1]);
        __builtin_amdgcn_s_setprio(0);
        vA_c = vA_n; kB_c0 = kB_n0; kB_c1 = kB_n1;
      }
      // o -> bufB (within-step pack); O^T: d = h*16+quad*4+r, a = mt*16+l16
#pragma unroll
      for (int mt = 0; mt < 2; ++mt) {
        float o0 = O[mt][0] * frcp(L4[mt][0]);
        float o1 = O[mt][1] * frcp(L4[mt][1]);
        float o2 = O[mt][2] * frcp(L4[mt][2]);
        float o3 = O[mt][3] * frcp(L4[mt][3]);
        unsigned long long ow =
            ((unsigned long long)cvtpk_bf16(o2, o3) << 32) | cvtpk_bf16(o0, o1);
        *(unsigned long long*)(s_bufB + (mt * 16 + l16) * 136 + h * 16 + quad * 4) = ow;
      }
    }
    __syncthreads();

    // ---- P6: LSTM gates (x-part folded through WO; weights in regs) ----
    {
      const int ni = wave;
      f32x4 gi[2], gf[2], gg[2], go[2];
#pragma unroll
      for (int mt = 0; mt < 2; ++mt) {
        gi[mt] = splat4(rB4[0]);
        gf[mt] = splat4(rB4[1]);
        gg[mt] = splat4(rB4[2]);
        go[mt] = splat4(rB4[3]);
      }
      __builtin_amdgcn_s_setprio(1);
#pragma unroll
      for (int kt = 0; kt < 4; ++kt)
#pragma unroll
        for (int mt = 0; mt < 2; ++mt) {
          short8 a8 = *(const short8*)(s_bufB + (mt * 16 + l16) * 136 + kt * 32 + quad * 8);
          gi[mt] = mfma_bf16(a8, rIH[kt][0], gi[mt]);
          gf[mt] = mfma_bf16(a8, rIH[kt][1], gf[mt]);
          gg[mt] = mfma_bf16(a8, rIH[kt][2], gg[mt]);
          go[mt] = mfma_bf16(a8, rIH[kt][3], go[mt]);
        }
#pragma unroll
      for (int kt = 0; kt < 4; ++kt)
#pragma unroll
        for (int mt = 0; mt < 2; ++mt) {
          short8 a8 = *(const short8*)(s_h + (mt * 16 + l16) * 136 + kt * 32 + quad * 8);
          gi[mt] = mfma_bf16(a8, rHH[kt][0], gi[mt]);
          gf[mt] = mfma_bf16(a8, rHH[kt][1], gf[mt]);
          gg[mt] = mfma_bf16(a8, rHH[kt][2], gg[mt]);
          go[mt] = mfma_bf16(a8, rHH[kt][3], go[mt]);
        }
      __builtin_amdgcn_s_setprio(0);
      float hnew[2][4];
#pragma unroll
      for (int mt = 0; mt < 2; ++mt)
#pragma unroll
        for (int r = 0; r < 4; ++r) {
          float iv = sigm(gi[mt][r]);
          float fv = sigm(gf[mt][r]);
          float gv = tanh_f(gg[mt][r]);
          float ov = sigm(go[mt][r]);
          float cn = fmaf(fv, c_reg[mt][r], iv * gv);
          float hv = ov * tanh_f(cn);
          int arow = mt * 16 + quad * 4 + r;
          float av = avl[mt][r];
          union { unsigned int u; float f; } ho;
          ho.u = ((unsigned int)s_h[arow * 136 + ni * 16 + l16]) << 16;
          c_reg[mt][r] = av * cn + (1.f - av) * c_reg[mt][r];
          hnew[mt][r] = av * hv + (1.f - av) * ho.f;
        }
      __syncthreads();  // all h reads (incl. MFMA A-frags) done before overwrite
#pragma unroll
      for (int mt = 0; mt < 2; ++mt)
#pragma unroll
        for (int r = 0; r < 4; ++r) {
          int arow = mt * 16 + quad * 4 + r;
          s_h[arow * 136 + ni * 16 + l16] = f2bf(hnew[mt][r]);  // recurrent: RNE
        }
    }
    __syncthreads();

    // ---- P7+P0 fused: state += h @ lin_w^T + lin_b; emit; next h1 ----
    {
      const unsigned short* hp = s_h + p7_a * 136 + p7_sub * 16;
      const float* lw = lnw + p7_oi * 128 + p7_sub * 16;
      short8 h0 = *(const short8*)hp;
      short8 h1 = *(const short8*)(hp + 8);
      float acc = 0.f;
#pragma unroll
      for (int k = 0; k < 8; ++k) {
        union { unsigned int u; float f; } hv;
        hv.u = ((unsigned int)(unsigned short)h0[k]) << 16;
        acc = fmaf(hv.f, lw[k], acc);
      }
#pragma unroll
      for (int k = 0; k < 8; ++k) {
        union { unsigned int u; float f; } hv;
        hv.u = ((unsigned int)(unsigned short)h1[k]) << 16;
        acc = fmaf(hv.f, lw[8 + k], acc);
      }
      acc += __shfl_xor(acc, 4);
      acc += __shfl_xor(acc, 2);
      acc += __shfl_xor(acc, 1);
      float ns = myst + acc + mylnb;
      myst = ns;
      if (p7_sub == 0)
        out[((size_t)(b * 64 + a0 + p7_a) * T + t) * 2 + p7_oi] = ns;
      // P0: h1(t+1) = relu(state @ w1^T + b1) -> bufA (within-step pack)
      float other = __shfl_xor(ns, 8);
      float st0 = p7_oi ? other : ns;
      float st1 = p7_oi ? ns : other;
      int a = tid >> 4, n0 = (tid & 15) * 8;
      const float* wp = w1 + n0 * 2;
      const float* bp = b1 + n0;
      float x[8];
#pragma unroll
      for (int j = 0; j < 8; ++j)
        x[j] = fmaxf(fmaf(wp[j * 2], st0, fmaf(wp[j * 2 + 1], st1, bp[j])), 0.f);
      union { short8 s; unsigned u[4]; } v;
#pragma unroll
      for (int j = 0; j < 4; ++j) v.u[j] = cvtpk_bf16(x[j * 2], x[j * 2 + 1]);
      *(short8*)(s_bufA + a * 136 + n0) = v.s;
    }
    __syncthreads();
  }
}

// ---------------------------------------------------------------- launch ----
extern "C" void kernel_launch(void* const* d_in, const int* in_sizes, int n_in,
                              void* d_out, int out_size, void* d_ws, size_t ws_size,
                              hipStream_t stream) {
  (void)in_sizes; (void)n_in; (void)out_size; (void)ws_size;
  const float* cf = (const float*)d_in[0];
  const int* cav = (const int*)d_in[1];
  const float* hid = (const float*)d_in[2];
  const float* ctx = (const float*)d_in[3];
  const float* emb = (const float*)d_in[4];
  const int* mav = (const int*)d_in[5];
  const int* ntp = (const int*)d_in[6];
  const float* w1 = (const float*)d_in[7];
  const float* b1 = (const float*)d_in[8];
  const float* w2 = (const float*)d_in[9];
  const float* b2 = (const float*)d_in[10];
  const float* w3 = (const float*)d_in[11];
  const float* b3 = (const float*)d_in[12];
  const float* wq = (const float*)d_in[13];
  const float* bq = (const float*)d_in[14];
  const float* wk = (const float*)d_in[15];
  const float* bk = (const float*)d_in[16];
  const float* wv = (const float*)d_in[17];
  const float* bv = (const float*)d_in[18];
  const float* wo = (const float*)d_in[19];
  const float* bo = (const float*)d_in[20];
  const float* wih = (const float*)d_in[21];  // w_ih
  const float* whh = (const float*)d_in[22];  // w_hh
  const float* bih = (const float*)d_in[23];  // b_ih
  const float* bhh = (const float*)d_in[24];  // b_hh
  const float* lnw = (const float*)d_in[25];
  const float* lnb = (const float*)d_in[26];

  char* ws = (char*)d_ws;
  unsigned char* K8 = (unsigned char*)(ws + 0);         // 8,388,608
  unsigned char* V8 = (unsigned char*)(ws + 8388608);   // 8,388,608
  unsigned short* W2s = (unsigned short*)(ws + 16777216);   // 16,384 B
  unsigned short* WQ3s = (unsigned short*)(ws + 16793600);  // 16,384 B
  unsigned short* WIHOs = (unsigned short*)(ws + 16809984); // 131,072 B
  unsigned short* WHHs = (unsigned short*)(ws + 16941056);  // 131,072 B
  float* B4p = (float*)(ws + 17072128);                     // 2,048 B
  float* BQ3S = (float*)(ws + 17074176);                    // 512 B

  (void)hipFuncSetAttribute((const void*)prep_kernel,
                            hipFuncAttributeMaxDynamicSharedMemorySize, 87040);
  (void)hipFuncSetAttribute((const void*)decoder_kernel,
                            hipFuncAttributeMaxDynamicSharedMemorySize, 162560);

  prep_kernel<<<1603, 256, 87040, stream>>>(
      emb, wk, bk, wv, bv, w2, whh, wih, wo, wq, w3, b3, bq, bo, bih, bhh,
      K8, V8, W2s, WHHs, WIHOs, WQ3s, B4p, BQ3S);
  decoder_kernel<<<256, 512, 162560, stream>>>(
      cf, cav, hid, ctx, mav, ntp, w1, b1, b2, K8, V8, W2s, WQ3s, WIHOs, WHHs,
      B4p, BQ3S, lnw, lnb, (float*)d_out);
}

// Round 10
// 1091.047 us; speedup vs baseline: 1.9475x; 1.0239x over previous
//
#include <hip/hip_runtime.h>
#include <cstdint>
#include <cstddef>

// Decoder_55654186222328 — MI355X, R18: h-buffer ping-pong (4 barriers/step)
// + prep LDS halved (3 blocks/CU).
// R17 post-mortem: total 1238->1117us (prep GEMM worked); decoder still 999us.
// R18a (decoder, 0 extra registers — the R14 lesson): during P6 the h1/qf8
// buffer is DEAD -> write h_new there and ping-pong the two buffers' roles
// each step (wave-uniform t&1 select, SGPR cselect). P6 reads buffer Y /
// writes buffer X -> disjoint -> its mid-barrier + drain deleted. 5->4
// barriers/step. Everything else byte-identical to R17's decoder.
// R18b (prep): the merged launch reserved 87KB LDS for EVERY block (1/CU,
// 1603 blocks in ~6 rounds). Two-phase staging (wk -> K-GEMM -> wv reuses the
// same buffer -> V-GEMM) cuts LDS to 52224 B -> 3 blocks/CU.
// 256 blocks (128 b x 2 agent halves of 32) x 512 threads, 1 block/CU,
// LDS 162560 B.

typedef short short8 __attribute__((ext_vector_type(8)));
typedef float f32x4 __attribute__((ext_vector_type(4)));

#define LOG2E 1.4426950408889634f
#define QSCALE 0.36067376022224085f /* log2(e)/4 */

__device__ __forceinline__ unsigned short f2bf(float f) {
  union { float f; unsigned int u; } v; v.f = f;
  unsigned int u = v.u;
  return (unsigned short)((u + 0x7fffu + ((u >> 16) & 1u)) >> 16);  // RNE
}
__device__ __forceinline__ unsigned cvtpk_bf16(float lo, float hi) {
  unsigned r;
  asm("v_cvt_pk_bf16_f32 %0, %1, %2" : "=v"(r) : "v"(lo), "v"(hi));
  return r;  // [15:0]=bf16(lo) [31:16]=bf16(hi); non-trans VOP3 (no hazard)
}
__device__ __forceinline__ float fexp2(float x) {
  return __builtin_amdgcn_exp2f(x);   // v_exp_f32, compiler-managed hazards
}
__device__ __forceinline__ float frcp(float x) {
  return __builtin_amdgcn_rcpf(x);    // v_rcp_f32, compiler-managed hazards
}
__device__ __forceinline__ float sigm(float x) {
  return frcp(1.f + fexp2(-LOG2E * x));
}
__device__ __forceinline__ float tanh_f(float x) {
  return 1.f - 2.f * frcp(1.f + fexp2(2.f * LOG2E * x));
}
__device__ __forceinline__ f32x4 splat4(float v) { f32x4 r = {v, v, v, v}; return r; }
__device__ __forceinline__ unsigned char f2fp8(float x) {
  return (unsigned char)__builtin_amdgcn_cvt_pk_fp8_f32(x, x, 0, false);
}
__device__ __forceinline__ f32x4 mfma_fp8(long a, long b, f32x4 c) {
  return __builtin_amdgcn_mfma_f32_16x16x32_fp8_fp8(a, b, c, 0, 0, 0);
}
__device__ __forceinline__ f32x4 mfma_bf16(short8 a, short8 b, f32x4 c) {
  return __builtin_amdgcn_mfma_f32_16x16x32_bf16(a, b, c, 0, 0, 0);
}

// ------------------------------------------------------------ prep (merged) --
// Block roles: [0,1024) kv-GEMM | [1024,1280) fold_wiho | [1280,1568) convert |
// [1568,1603) fold_wq3b. All independent -> concurrent in one launch.
// K8[b][m][128] fp8; V8[b][d][512] fp8 (transposed, m-permuted within each
// 32-token chunk: slot s holds token pi(s), pi(8q+j)=4q+j (j<4) else
// 16+4q+(j-4)).
// kv-role LDS (two-phase weight reuse): s_e bf16[64][136] @0 (17408) |
// s_w bf16[128][136] @17408 (34816). Total 52224 B -> 3 blocks/CU.
__global__ __launch_bounds__(256) void prep_kernel(
    const float* __restrict__ emb, const float* __restrict__ wk,
    const float* __restrict__ bk, const float* __restrict__ wv,
    const float* __restrict__ bv,
    const float* __restrict__ w2, const float* __restrict__ whh,
    const float* __restrict__ wih, const float* __restrict__ wo,
    const float* __restrict__ wq, const float* __restrict__ w3,
    const float* __restrict__ b3, const float* __restrict__ bq,
    const float* __restrict__ bo, const float* __restrict__ bih,
    const float* __restrict__ bhh,
    unsigned char* __restrict__ K8, unsigned char* __restrict__ V8,
    unsigned short* __restrict__ W2, unsigned short* __restrict__ WHH,
    unsigned short* __restrict__ WIHO, unsigned short* __restrict__ WQ3,
    float* __restrict__ B4p, float* __restrict__ BQ3S) {
  extern __shared__ char smem[];
  const int tid = threadIdx.x;
  const int blk = blockIdx.x;

  if (blk < 1024) {  // ---- kv role: bf16 MFMA GEMM, two-phase weights ----
    unsigned short* s_e = (unsigned short*)smem;            // [64][136]
    unsigned short* s_w = (unsigned short*)(smem + 17408);  // [128][136]
    const int b = blk >> 3;
    const int m0 = (blk & 7) * 64;
    const int wave = tid >> 6;
    const int lane = tid & 63;
    const int quad = lane >> 4;
    const int l16 = lane & 15;

    // stage e + wk (pairs -> u32 writes; col even so 4B-aligned)
    for (int i = tid; i < 4096; i += 256) {
      int j = i * 2, row = j >> 7, col = j & 127;
      const float* p = emb + (size_t)(b * 512 + m0 + row) * 128 + col;
      *(unsigned*)(s_e + row * 136 + col) = cvtpk_bf16(p[0], p[1]);
    }
    for (int i = tid; i < 8192; i += 256) {
      int j = i * 2, row = j >> 7, col = j & 127;
      *(unsigned*)(s_w + row * 136 + col) =
          cvtpk_bf16(wk[row * 128 + col], wk[row * 128 + col + 1]);
    }
    __syncthreads();

    {  // K-phase: C[m][d] = e @ wk^T  (M64 N128 K128; wave = m-tile)
      const int mt = wave;
      short8 a8[4];
#pragma unroll
      for (int kt = 0; kt < 4; ++kt)
        a8[kt] = *(const short8*)(s_e + (mt * 16 + l16) * 136 + kt * 32 + quad * 8);
#pragma unroll
      for (int nt = 0; nt < 8; ++nt) {
        f32x4 acc = {0.f, 0.f, 0.f, 0.f};
#pragma unroll
        for (int kt = 0; kt < 4; ++kt) {
          short8 b8 = *(const short8*)(s_w + (nt * 16 + l16) * 136 + kt * 32 + quad * 8);
          acc = mfma_bf16(a8[kt], b8, acc);
        }
        const int d = nt * 16 + l16;
        const float bkd = bk[d];
#pragma unroll
        for (int r = 0; r < 4; ++r)
          K8[(size_t)(b * 512 + m0 + mt * 16 + quad * 4 + r) * 128 + d] =
              f2fp8(acc[r] + bkd);
      }
    }
    __syncthreads();  // K-phase reads of s_w done before wv overwrite
    for (int i = tid; i < 8192; i += 256) {
      int j = i * 2, row = j >> 7, col = j & 127;
      *(unsigned*)(s_w + row * 136 + col) =
          cvtpk_bf16(wv[row * 128 + col], wv[row * 128 + col + 1]);
    }
    __syncthreads();
    {  // V-phase: C[d][m] = wv @ e^T (M128 N64 K128; born transposed)
      const int dt0 = wave * 2;
#pragma unroll
      for (int dt = dt0; dt < dt0 + 2; ++dt) {
        short8 a8[4];
#pragma unroll
        for (int kt = 0; kt < 4; ++kt)
          a8[kt] = *(const short8*)(s_w + (dt * 16 + l16) * 136 + kt * 32 + quad * 8);
#pragma unroll
        for (int nt = 0; nt < 4; ++nt) {
          f32x4 acc = {0.f, 0.f, 0.f, 0.f};
#pragma unroll
          for (int kt = 0; kt < 4; ++kt) {
            short8 b8 = *(const short8*)(s_e + (nt * 16 + l16) * 136 + kt * 32 + quad * 8);
            acc = mfma_bf16(a8[kt], b8, acc);
          }
          const int m = m0 + nt * 16 + l16;
          const int ml = m & 31;
          const int sperm = (ml < 16) ? (((ml >> 2) << 3) | (ml & 3))
                                      : ((((ml - 16) >> 2) << 3) | ((ml - 16) & 3) | 4);
          const int mpos = (m & ~31) | sperm;
#pragma unroll
          for (int r = 0; r < 4; ++r) {
            const int d = dt * 16 + quad * 4 + r;
            V8[(size_t)(b * 128 + d) * 512 + mpos] = f2fp8(acc[r] + bv[d]);
          }
        }
      }
    }
  } else if (blk < 1280) {  // ---- fold WIHO: WIHO[r][d] = wih@wo (bf16) ----
    int i = (blk - 1024) * 256 + tid;  // 65536
    int r = i >> 7, d = i & 127;
    float acc = 0.f;
    for (int n = 0; n < 128; ++n)
      acc = fmaf(wih[r * 128 + n], wo[n * 128 + d], acc);
    WIHO[i] = f2bf(acc);
  } else if (blk < 1568) {  // ---- convert W2 + WHH -> bf16 ----
    int i = (blk - 1280) * 256 + tid;
    if (i < 8192) W2[i] = f2bf(w2[i]);
    else if (i < 73728) WHH[i - 8192] = f2bf(whh[i - 8192]);
  } else {  // ---- fold WQ3 + biases ----
    int i = (blk - 1568) * 256 + tid;
    if (i < 8192) {
      int n = i >> 6, k = i & 63;
      float acc = 0.f;
      for (int j = 0; j < 128; ++j) acc = fmaf(wq[n * 128 + j], w3[j * 64 + k], acc);
      WQ3[i] = f2bf(acc * QSCALE);
    } else if (i < 8704) {
      int r = i - 8192;
      float acc = bih[r] + bhh[r];
      for (int n = 0; n < 128; ++n) acc = fmaf(wih[r * 128 + n], bo[n], acc);
      B4p[r] = acc;
    } else if (i < 8832) {
      int n = i - 8704;
      float acc = bq[n];
      for (int j = 0; j < 128; ++j) acc = fmaf(wq[n * 128 + j], b3[j], acc);
      BQ3S[n] = acc * QSCALE;
    }
  }
}

// ---------------------------------------------------------------- decoder ----
// grid 256 = 128 b x 2 agent-halves (32 agents). 512 threads = 8 waves.
// LDS (162560 B, 1 block/CU):
//   sK    @0      fp8 [512][128] XOR-swz  65536   (persistent)
//   sV    @65536  fp8 [128][512] XOR-swz  65536   (persistent, transposed+pi)
//   bufV  @131072 u16 [32][136]            8704   \ ping-pong pair: one holds
//   bufU  @148480 u16 [32][136]            8704   / h(t), other h1|qf8|h(t+1)
//   bufB  @139776 u16 [32][136]            8704   (o)
//   zone  @157184 h2 u16 [32][72]          4608
//   maskb @162048 u8 [512]                  512
// Step t: hb = (t&1)?V:U holds h(t); xb = the other. P1 reads h1 from xb;
// P3 writes qf8 into xb; P4 reads qf8; P6 reads h from hb + o from bufB,
// writes h(t+1) into xb (qf8 dead; disjoint from reads -> NO mid-barrier);
// P7 reads h(t+1) from xb; P0 writes h1(t+1) into hb (dead). Roles swap.
// Per-step barriers (4): P1|P3+P4|P6|P7+P0.
__global__ __launch_bounds__(512, 2) void decoder_kernel(
    const float* __restrict__ cf, const int* __restrict__ cav,
    const float* __restrict__ hid,
    const float* __restrict__ ctx, const int* __restrict__ mav,
    const int* __restrict__ ntp,
    const float* __restrict__ w1, const float* __restrict__ b1,
    const float* __restrict__ b2,
    const unsigned char* __restrict__ K8, const unsigned char* __restrict__ V8,
    const unsigned short* __restrict__ W2, const unsigned short* __restrict__ WQ3,
    const unsigned short* __restrict__ WIHO, const unsigned short* __restrict__ WHH,
    const float* __restrict__ B4p, const float* __restrict__ BQ3S,
    const float* __restrict__ lnw, const float* __restrict__ lnb,
    float* __restrict__ out) {
  extern __shared__ char smem[];
  unsigned short* s_bufV = (unsigned short*)(smem + 131072);
  unsigned short* s_bufB = (unsigned short*)(smem + 139776);
  unsigned short* s_bufU = (unsigned short*)(smem + 148480);
  unsigned short* s_h2 = (unsigned short*)(smem + 157184);
  unsigned char* s_maskb = (unsigned char*)(smem + 162048);

  const int tid = threadIdx.x;
  const int wave = tid >> 6;
  const int lane = tid & 63;
  const int quad = lane >> 4;
  const int l16 = lane & 15;

  const int b = blockIdx.x & 127;
  const int a0 = (blockIdx.x >> 7) * 32;
  const int T = *ntp;
  const f32x4 zero4 = {0.f, 0.f, 0.f, 0.f};
  const long kOnes = 0x3838383838383838L;  // fp8 e4m3 1.0 x8

  // ---- preload persistent K/V into LDS with XOR swizzle ----
  {
    const unsigned long long* Kg = (const unsigned long long*)(K8 + (size_t)b * 65536);
    for (int i = tid; i < 8192; i += 512) {
      int tok = i >> 4, seg = i & 15;
      *(unsigned long long*)(smem + tok * 128 + ((seg * 8) ^ ((tok & 15) * 8))) =
          Kg[(size_t)tok * 16 + seg];
    }
    const unsigned long long* Vg = (const unsigned long long*)(V8 + (size_t)b * 65536);
    for (int i = tid; i < 8192; i += 512) {
      int d = i >> 6, seg = i & 63;
      *(unsigned long long*)(smem + 65536 + d * 512 + ((seg * 8) ^ ((d & 15) * 8))) =
          Vg[(size_t)d * 64 + seg];
    }
  }
  // ---- init ----
  s_maskb[tid] = mav[b * 512 + tid] ? 1 : 0;
  {  // h0 -> U (step 0's h-buffer) — recurrent init: software RNE
    int idx = tid * 8;
    int a = idx >> 7, n0 = idx & 127;
    const float* hp = hid + (size_t)(b * 64 + a0 + a) * 128 + n0;
    short8 v;
#pragma unroll
    for (int j = 0; j < 8; ++j) v[j] = (short)f2bf(hp[j]);
    *(short8*)(s_bufU + a * 136 + n0) = v;
  }
  float c_reg[2][4], avl[2][4];
#pragma unroll
  for (int mt = 0; mt < 2; ++mt)
#pragma unroll
    for (int r = 0; r < 4; ++r) {
      int a = mt * 16 + quad * 4 + r;
      c_reg[mt][r] = ctx[(size_t)(b * 64 + a0 + a) * 128 + wave * 16 + l16];
      avl[mt][r] = (cav[b * 64 + a0 + a] != 0) ? 1.f : 0.f;
    }

  // ---- persistent register-cached weights (step-invariant) ----
  const int wrow = wave * 16 + l16;
  short8 rIH[4][4], rHH[4][4];
#pragma unroll
  for (int kt = 0; kt < 4; ++kt)
#pragma unroll
    for (int g = 0; g < 4; ++g) {
      rIH[kt][g] = *(const short8*)(WIHO + ((g * 128 + wrow) * 128 + kt * 32 + quad * 8));
      rHH[kt][g] = *(const short8*)(WHH + ((g * 128 + wrow) * 128 + kt * 32 + quad * 8));
    }
  short8 rWQ3[2];
#pragma unroll
  for (int kt = 0; kt < 2; ++kt)
    rWQ3[kt] = *(const short8*)(WQ3 + (wrow * 64 + kt * 32 + quad * 8));
  float rB4[4];
#pragma unroll
  for (int g = 0; g < 4; ++g) rB4[g] = B4p[g * 128 + wrow];
  const float rBQ3 = BQ3S[wrow];
  const float rB2 = b2[(wave & 3) * 16 + l16];

  // ---- fused-P7/P0 per-thread constants + register state ----
  const int p7_o = tid >> 3, p7_sub = tid & 7;
  const int p7_a = p7_o >> 1, p7_oi = p7_o & 1;
  const float mylnb = lnb[p7_oi];
  float myst = cf[(size_t)(b * 64 + a0 + p7_a) * 2 + p7_oi];

  __syncthreads();

  // per-lane mask flags: bit i set when token i*16+l16 is NOT available.
  unsigned mflags = 0;
#pragma unroll
  for (int i = 0; i < 32; ++i)
    if (!s_maskb[i * 16 + l16]) mflags |= (1u << i);

  // ---- initial h1 from initial state -> V (step 0's xb) ----
  {
    float other = __shfl_xor(myst, 8);
    float st0 = p7_oi ? other : myst;
    float st1 = p7_oi ? myst : other;
    int a = tid >> 4, n0 = (tid & 15) * 8;
    const float* wp = w1 + n0 * 2;
    const float* bp = b1 + n0;
    float x[8];
#pragma unroll
    for (int j = 0; j < 8; ++j)
      x[j] = fmaxf(fmaf(wp[j * 2], st0, fmaf(wp[j * 2 + 1], st1, bp[j])), 0.f);
    union { short8 s; unsigned u[4]; } v;
#pragma unroll
    for (int j = 0; j < 4; ++j) v.u[j] = cvtpk_bf16(x[j * 2], x[j * 2 + 1]);
    *(short8*)(s_bufV + a * 136 + n0) = v.s;
  }
  __syncthreads();

#pragma unroll 1
  for (int t = 0; t < T; ++t) {
    unsigned short* hb = (t & 1) ? s_bufV : s_bufU;  // holds h(t)
    unsigned short* xb = (t & 1) ? s_bufU : s_bufV;  // h1 | qf8 | h(t+1)

    // ---- P1: h2 = relu(h1 @ w2^T + b2)  M32 N64 K128 -> zone ----
    {
      int mt = wave >> 2, nt = wave & 3;
      f32x4 acc = splat4(rB2);
#pragma unroll
      for (int kt = 0; kt < 4; ++kt) {
        short8 a8 = *(const short8*)(xb + (mt * 16 + l16) * 136 + kt * 32 + quad * 8);
        short8 b8 = *(const short8*)(W2 + ((nt * 16 + l16) * 128 + kt * 32 + quad * 8));
        acc = mfma_bf16(a8, b8, acc);
      }
      unsigned pk01 = cvtpk_bf16(fmaxf(acc[0], 0.f), fmaxf(acc[1], 0.f));
      unsigned pk23 = cvtpk_bf16(fmaxf(acc[2], 0.f), fmaxf(acc[3], 0.f));
      unsigned short* hbp = s_h2 + (mt * 16 + quad * 4) * 72 + nt * 16 + l16;
      hbp[0] = (unsigned short)pk01;
      hbp[72] = (unsigned short)(pk01 >> 16);
      hbp[144] = (unsigned short)pk23;
      hbp[216] = (unsigned short)(pk23 >> 16);
    }
    __syncthreads();

    // ---- P3: q = h2 @ WQ3^T + bq3 -> fp8 in xb bytes (h1 dead) ----
    // wave nt==h produces exactly head h's q-columns -> no barrier before P4.
    unsigned char* s_q8 = (unsigned char*)xb;
    {
#pragma unroll
      for (int mt = 0; mt < 2; ++mt) {
        f32x4 acc = splat4(rBQ3);
#pragma unroll
        for (int kt = 0; kt < 2; ++kt) {
          short8 a8 = *(const short8*)(s_h2 + (mt * 16 + l16) * 72 + kt * 32 + quad * 8);
          acc = mfma_bf16(a8, rWQ3[kt], acc);
        }
#pragma unroll
        for (int r = 0; r < 4; ++r)
          s_q8[(mt * 16 + quad * 4 + r) * 136 + wave * 16 + l16] = f2fp8(acc[r]);
      }
    }
    __asm__ volatile("s_waitcnt lgkmcnt(0)" ::: "memory");
    __builtin_amdgcn_sched_barrier(0);

    // ---- P4: attention — swapped-operand MFMA, P in registers, prefetched ----
    {
      const int h = wave;
      const char* sKb = (const char*)smem;
      const char* sVrow = (const char*)(smem + 65536) + (h * 16 + l16) * 512;
      long qA[2];
#pragma unroll
      for (int mt = 0; mt < 2; ++mt)
        qA[mt] = (quad < 2)
                     ? *(const long*)(s_q8 + (mt * 16 + l16) * 136 + h * 16 + quad * 8)
                     : (quad == 2 ? 0xF8L : 0L);  // byte0 = fp8 -256
      const int koff = (h * 16 + quad * 8) ^ (l16 * 8);
      f32x4 O[2], L4[2];
      O[0] = zero4; O[1] = zero4; L4[0] = zero4; L4[1] = zero4;
      // prefetch chunk 0
      long vA_c = *(const long*)(sVrow + ((quad * 8) ^ (l16 * 8)));
      long kB_c0 = 0L, kB_c1 = 0L;
      if (quad < 2) {
        kB_c0 = *(const long*)(sKb + (size_t)l16 * 128 + koff);
        kB_c1 = *(const long*)(sKb + (size_t)(16 + l16) * 128 + koff);
      }
#pragma unroll 4
      for (int c = 0; c < 16; ++c) {
        long vA_n = 0L, kB_n0 = 0L, kB_n1 = 0L;
        if (c < 15) {
          vA_n = *(const long*)(sVrow + (((c + 1) * 32 + quad * 8) ^ (l16 * 8)));
          if (quad < 2) {
            kB_n0 = *(const long*)(sKb + (size_t)((c + 1) * 32 + l16) * 128 + koff);
            kB_n1 = *(const long*)(sKb + (size_t)((c + 1) * 32 + 16 + l16) * 128 + koff);
          }
        }
        long kB0 = kB_c0, kB1 = kB_c1;
        if (quad == 2) {
          kB0 = ((mflags >> (c * 2)) & 1u) ? 0x38L : 0L;      // fp8 1.0 flag
          kB1 = ((mflags >> (c * 2 + 1)) & 1u) ? 0x38L : 0L;
        }
        __builtin_amdgcn_s_setprio(1);
        f32x4 S2[2][2];
        S2[0][0] = mfma_fp8(kB0, qA[0], zero4);
        S2[0][1] = mfma_fp8(kB0, qA[1], zero4);
        S2[1][0] = mfma_fp8(kB1, qA[0], zero4);
        S2[1][1] = mfma_fp8(kB1, qA[1], zero4);
        __builtin_amdgcn_s_setprio(0);
        long pB[2];
#pragma unroll
        for (int mt = 0; mt < 2; ++mt) {
          unsigned w0 = (unsigned)__builtin_amdgcn_cvt_pk_fp8_f32(
              fexp2(S2[0][mt][0]), fexp2(S2[0][mt][1]), 0, false);
          w0 = (unsigned)__builtin_amdgcn_cvt_pk_fp8_f32(
              fexp2(S2[0][mt][2]), fexp2(S2[0][mt][3]), (int)w0, true);
          unsigned w1v = (unsigned)__builtin_amdgcn_cvt_pk_fp8_f32(
              fexp2(S2[1][mt][0]), fexp2(S2[1][mt][1]), 0, false);
          w1v = (unsigned)__builtin_amdgcn_cvt_pk_fp8_f32(
              fexp2(S2[1][mt][2]), fexp2(S2[1][mt][3]), (int)w1v, true);
          pB[mt] = (long)(((unsigned long long)w1v << 32) | (unsigned long long)w0);
        }
        __builtin_amdgcn_s_setprio(1);
        O[0] = mfma_fp8(vA_c, pB[0], O[0]);     // O^T: rows d-local, cols a
        L4[0] = mfma_fp8(kOnes, pB[0], L4[0]);
        O[1] = mfma_fp8(vA_c, pB[1], O[1]);
        L4[1] = mfma_fp8(kOnes, pB[1], L4[1]);
        __builtin_amdgcn_s_setprio(0);
        vA_c = vA_n; kB_c0 = kB_n0; kB_c1 = kB_n1;
      }
      // o -> bufB (within-step pack); O^T: d = h*16+quad*4+r, a = mt*16+l16
#pragma unroll
      for (int mt = 0; mt < 2; ++mt) {
        float o0 = O[mt][0] * frcp(L4[mt][0]);
        float o1 = O[mt][1] * frcp(L4[mt][1]);
        float o2 = O[mt][2] * frcp(L4[mt][2]);
        float o3 = O[mt][3] * frcp(L4[mt][3]);
        unsigned long long ow =
            ((unsigned long long)cvtpk_bf16(o2, o3) << 32) | cvtpk_bf16(o0, o1);
        *(unsigned long long*)(s_bufB + (mt * 16 + l16) * 136 + h * 16 + quad * 4) = ow;
      }
    }
    __syncthreads();

    // ---- P6: LSTM gates; reads h from hb + o from bufB, writes h(t+1) to
    // xb (qf8 dead; disjoint from all P6 reads -> no mid-barrier). ----
    {
      const int ni = wave;
      f32x4 gi[2], gf[2], gg[2], go[2];
#pragma unroll
      for (int mt = 0; mt < 2; ++mt) {
        gi[mt] = splat4(rB4[0]);
        gf[mt] = splat4(rB4[1]);
        gg[mt] = splat4(rB4[2]);
        go[mt] = splat4(rB4[3]);
      }
      __builtin_amdgcn_s_setprio(1);
#pragma unroll
      for (int kt = 0; kt < 4; ++kt)
#pragma unroll
        for (int mt = 0; mt < 2; ++mt) {
          short8 a8 = *(const short8*)(s_bufB + (mt * 16 + l16) * 136 + kt * 32 + quad * 8);
          gi[mt] = mfma_bf16(a8, rIH[kt][0], gi[mt]);
          gf[mt] = mfma_bf16(a8, rIH[kt][1], gf[mt]);
          gg[mt] = mfma_bf16(a8, rIH[kt][2], gg[mt]);
          go[mt] = mfma_bf16(a8, rIH[kt][3], go[mt]);
        }
#pragma unroll
      for (int kt = 0; kt < 4; ++kt)
#pragma unroll
        for (int mt = 0; mt < 2; ++mt) {
          short8 a8 = *(const short8*)(hb + (mt * 16 + l16) * 136 + kt * 32 + quad * 8);
          gi[mt] = mfma_bf16(a8, rHH[kt][0], gi[mt]);
          gf[mt] = mfma_bf16(a8, rHH[kt][1], gf[mt]);
          gg[mt] = mfma_bf16(a8, rHH[kt][2], gg[mt]);
          go[mt] = mfma_bf16(a8, rHH[kt][3], go[mt]);
        }
      __builtin_amdgcn_s_setprio(0);
#pragma unroll
      for (int mt = 0; mt < 2; ++mt)
#pragma unroll
        for (int r = 0; r < 4; ++r) {
          float iv = sigm(gi[mt][r]);
          float fv = sigm(gf[mt][r]);
          float gv = tanh_f(gg[mt][r]);
          float ov = sigm(go[mt][r]);
          float cn = fmaf(fv, c_reg[mt][r], iv * gv);
          float hv = ov * tanh_f(cn);
          int arow = mt * 16 + quad * 4 + r;
          float av = avl[mt][r];
          union { unsigned int u; float f; } ho;
          ho.u = ((unsigned int)hb[arow * 136 + ni * 16 + l16]) << 16;
          c_reg[mt][r] = av * cn + (1.f - av) * c_reg[mt][r];
          float hn = av * hv + (1.f - av) * ho.f;
          xb[arow * 136 + ni * 16 + l16] = f2bf(hn);  // recurrent: RNE
        }
    }
    __syncthreads();

    // ---- P7+P0 fused: state += h @ lin_w^T + lin_b; emit; next h1 ----
    {
      const unsigned short* hp = xb + p7_a * 136 + p7_sub * 16;
      const float* lw = lnw + p7_oi * 128 + p7_sub * 16;
      short8 h0 = *(const short8*)hp;
      short8 h1 = *(const short8*)(hp + 8);
      float acc = 0.f;
#pragma unroll
      for (int k = 0; k < 8; ++k) {
        union { unsigned int u; float f; } hv;
        hv.u = ((unsigned int)(unsigned short)h0[k]) << 16;
        acc = fmaf(hv.f, lw[k], acc);
      }
#pragma unroll
      for (int k = 0; k < 8; ++k) {
        union { unsigned int u; float f; } hv;
        hv.u = ((unsigned int)(unsigned short)h1[k]) << 16;
        acc = fmaf(hv.f, lw[8 + k], acc);
      }
      acc += __shfl_xor(acc, 4);
      acc += __shfl_xor(acc, 2);
      acc += __shfl_xor(acc, 1);
      float ns = myst + acc + mylnb;
      myst = ns;
      if (p7_sub == 0)
        out[((size_t)(b * 64 + a0 + p7_a) * T + t) * 2 + p7_oi] = ns;
      // P0: h1(t+1) = relu(state @ w1^T + b1) -> hb (h(t) dead)
      float other = __shfl_xor(ns, 8);
      float st0 = p7_oi ? other : ns;
      float st1 = p7_oi ? ns : other;
      int a = tid >> 4, n0 = (tid & 15) * 8;
      const float* wp = w1 + n0 * 2;
      const float* bp = b1 + n0;
      float x[8];
#pragma unroll
      for (int j = 0; j < 8; ++j)
        x[j] = fmaxf(fmaf(wp[j * 2], st0, fmaf(wp[j * 2 + 1], st1, bp[j])), 0.f);
      union { short8 s; unsigned u[4]; } v;
#pragma unroll
      for (int j = 0; j < 4; ++j) v.u[j] = cvtpk_bf16(x[j * 2], x[j * 2 + 1]);
      *(short8*)(hb + a * 136 + n0) = v.s;
    }
    __syncthreads();
  }
}

// ---------------------------------------------------------------- launch ----
extern "C" void kernel_launch(void* const* d_in, const int* in_sizes, int n_in,
                              void* d_out, int out_size, void* d_ws, size_t ws_size,
                              hipStream_t stream) {
  (void)in_sizes; (void)n_in; (void)out_size; (void)ws_size;
  const float* cf = (const float*)d_in[0];
  const int* cav = (const int*)d_in[1];
  const float* hid = (const float*)d_in[2];
  const float* ctx = (const float*)d_in[3];
  const float* emb = (const float*)d_in[4];
  const int* mav = (const int*)d_in[5];
  const int* ntp = (const int*)d_in[6];
  const float* w1 = (const float*)d_in[7];
  const float* b1 = (const float*)d_in[8];
  const float* w2 = (const float*)d_in[9];
  const float* b2 = (const float*)d_in[10];
  const float* w3 = (const float*)d_in[11];
  const float* b3 = (const float*)d_in[12];
  const float* wq = (const float*)d_in[13];
  const float* bq = (const float*)d_in[14];
  const float* wk = (const float*)d_in[15];
  const float* bk = (const float*)d_in[16];
  const float* wv = (const float*)d_in[17];
  const float* bv = (const float*)d_in[18];
  const float* wo = (const float*)d_in[19];
  const float* bo = (const float*)d_in[20];
  const float* wih = (const float*)d_in[21];  // w_ih
  const float* whh = (const float*)d_in[22];  // w_hh
  const float* bih = (const float*)d_in[23];  // b_ih
  const float* bhh = (const float*)d_in[24];  // b_hh
  const float* lnw = (const float*)d_in[25];
  const float* lnb = (const float*)d_in[26];

  char* ws = (char*)d_ws;
  unsigned char* K8 = (unsigned char*)(ws + 0);         // 8,388,608
  unsigned char* V8 = (unsigned char*)(ws + 8388608);   // 8,388,608
  unsigned short* W2s = (unsigned short*)(ws + 16777216);   // 16,384 B
  unsigned short* WQ3s = (unsigned short*)(ws + 16793600);  // 16,384 B
  unsigned short* WIHOs = (unsigned short*)(ws + 16809984); // 131,072 B
  unsigned short* WHHs = (unsigned short*)(ws + 16941056);  // 131,072 B
  float* B4p = (float*)(ws + 17072128);                     // 2,048 B
  float* BQ3S = (float*)(ws + 17074176);                    // 512 B

  (void)hipFuncSetAttribute((const void*)prep_kernel,
                            hipFuncAttributeMaxDynamicSharedMemorySize, 52224);
  (void)hipFuncSetAttribute((const void*)decoder_kernel,
                            hipFuncAttributeMaxDynamicSharedMemorySize, 162560);

  prep_kernel<<<1603, 256, 52224, stream>>>(
      emb, wk, bk, wv, bv, w2, whh, wih, wo, wq, w3, b3, bq, bo, bih, bhh,
      K8, V8, W2s, WHHs, WIHOs, WQ3s, B4p, BQ3S);
  decoder_kernel<<<256, 512, 162560, stream>>>(
      cf, cav, hid, ctx, mav, ntp, w1, b1, b2, K8, V8, W2s, WQ3s, WIHOs, WHHs,
      B4p, BQ3S, lnw, lnb, (float*)d_out);
}